// Round 8
// baseline (220.957 us; speedup 1.0000x reference)
//
#include <hip/hip_runtime.h>
#include <hip/hip_bf16.h>
#include <math.h>

// Problem constants (fixed by reference).
constexpr int NVOX = 40000;
constexpr int NQRY = 8192;
constexpr int KK   = 96;
constexpr int CH   = 128;
constexpr int FFD  = 256;

typedef __attribute__((ext_vector_type(8))) short short8;
typedef __attribute__((ext_vector_type(4))) float float4v;

__device__ inline float bflo(unsigned u) { return __uint_as_float(u << 16); }
__device__ inline float bfhi(unsigned u) { return __uint_as_float(u & 0xffff0000u); }
__device__ inline unsigned short f2bf(float x) {
  union { float f; unsigned u; } a; a.f = x;
  const unsigned r = a.u + 0x7fffu + ((a.u >> 16) & 1u);  // round-to-nearest-even
  return (unsigned short)(r >> 16);
}
__device__ inline unsigned pack2(float lo, float hi) {
  return (unsigned)f2bf(lo) | ((unsigned)f2bf(hi) << 16);
}

#if __has_builtin(__builtin_amdgcn_fdot2_f32_bf16)
#define HAVE_DOT2_BF16 1
typedef __bf16 bf16x2v __attribute__((ext_vector_type(2)));
__device__ inline float dot2bf(unsigned kv, unsigned qq, float acc) {
  return __builtin_amdgcn_fdot2_f32_bf16(
      __builtin_bit_cast(bf16x2v, kv), __builtin_bit_cast(bf16x2v, qq), acc, false);
}
#else
#define HAVE_DOT2_BF16 0
#endif

// ---------------------------------------------------------------------------
// Kernel 1: prep (merged) —
//  blocks [0, NVOX/16):         per-voxel LN + relu(key-pos) -> Gb bf16
//  blocks [NVOX/16, +8):        Wkv -> Wb bf16
//  blocks [NVOX/16+8, +24):     epilogue weights -> Eb bf16
//  blocks [NVOX/16+32, +512):   q = relu(qc@q_pos_w.T+b) @ wq.T + bq -> qb f32
// ---------------------------------------------------------------------------
__global__ __launch_bounds__(256) void k_prep(
    const float* __restrict__ vfeat, const float* __restrict__ vcoord,
    const float* __restrict__ n1g, const float* __restrict__ n1b,
    const float* __restrict__ kpw, const float* __restrict__ kpb,
    const float* __restrict__ in_w, const float* __restrict__ in_b,
    const float* __restrict__ ow, const float* __restrict__ l1w,
    const float* __restrict__ l2w, const float* __restrict__ fw,
    const float* __restrict__ qcoord,
    const float* __restrict__ qpw, const float* __restrict__ qpb,
    __hip_bfloat16* __restrict__ Gb, __hip_bfloat16* __restrict__ Wb,
    __hip_bfloat16* __restrict__ Eb, float* __restrict__ qout) {
  const int b = blockIdx.x;
  const int t = threadIdx.x;
  if (b < NVOX/16) {
    const int vloc = t >> 4;
    const int l    = t & 15;
    const int j = b * 16 + vloc;
    const float4* vrow = reinterpret_cast<const float4*>(vfeat + (size_t)j * CH);
    const float4 x0 = vrow[l*2], x1 = vrow[l*2+1];
    float s  = x0.x+x0.y+x0.z+x0.w + x1.x+x1.y+x1.z+x1.w;
    float ss = x0.x*x0.x+x0.y*x0.y+x0.z*x0.z+x0.w*x0.w
             + x1.x*x1.x+x1.y*x1.y+x1.z*x1.z+x1.w*x1.w;
    #pragma unroll
    for (int m = 8; m >= 1; m >>= 1) { s += __shfl_xor(s, m); ss += __shfl_xor(ss, m); }
    const float mean = s * (1.0f/CH);
    const float var  = ss * (1.0f/CH) - mean*mean;
    const float rstd = 1.0f / sqrtf(var + 1e-5f);
    const float c0 = vcoord[j*3+0], c1 = vcoord[j*3+1], c2 = vcoord[j*3+2];
    const float xv[8] = {x0.x,x0.y,x0.z,x0.w,x1.x,x1.y,x1.z,x1.w};
    float gv[8];
    #pragma unroll
    for (int u = 0; u < 8; u++) {
      const int c = l*8 + u;
      const float vf = (xv[u] - mean) * rstd * n1g[c] + n1b[c];
      const float kp = fmaf(c0, kpw[c*3+0], fmaf(c1, kpw[c*3+1], fmaf(c2, kpw[c*3+2], kpb[c])));
      gv[u] = vf + fmaxf(kp, 0.0f);
    }
    const uint4 pk = make_uint4(pack2(gv[0],gv[1]), pack2(gv[2],gv[3]),
                                pack2(gv[4],gv[5]), pack2(gv[6],gv[7]));
    *reinterpret_cast<uint4*>(Gb + (size_t)j*CH + l*8) = pk;
  } else if (b < NVOX/16 + 32) {
    const int idx = b - NVOX/16;
    const float* src;
    __hip_bfloat16* dst;
    if (idx < 8) {
      const int e = (idx * 256 + t) * 16;
      src = in_w + (size_t)CH*CH + e;
      dst = Wb + e;
    } else {
      const int f = ((idx - 8) * 256 + t) * 16;   // 0..98303
      dst = Eb + f;
      if      (f < 16384) src = ow  + f;
      else if (f < 49152) src = l1w + (f - 16384);
      else if (f < 81920) src = l2w + (f - 49152);
      else                src = fw  + (f - 81920);
    }
    float v[16];
    #pragma unroll
    for (int u = 0; u < 4; u++) {
      const float4 fq = *reinterpret_cast<const float4*>(src + u*4);
      v[u*4+0]=fq.x; v[u*4+1]=fq.y; v[u*4+2]=fq.z; v[u*4+3]=fq.w;
    }
    uint4* o = reinterpret_cast<uint4*>(dst);
    o[0] = make_uint4(pack2(v[0],v[1]), pack2(v[2],v[3]),
                      pack2(v[4],v[5]), pack2(v[6],v[7]));
    o[1] = make_uint4(pack2(v[8],v[9]), pack2(v[10],v[11]),
                      pack2(v[12],v[13]), pack2(v[14],v[15]));
  } else {
    // q projection: 16 queries per block.
    __shared__ float qf[16][CH];
    const int qbase = (b - (NVOX/16 + 32)) * 16;
    #pragma unroll
    for (int i = 0; i < 8; i++) {
      const int e = t + 256*i;
      const int qv = e >> 7, c = e & 127;
      const int qq = qbase + qv;
      const float v = fmaf(qcoord[qq*3+0], qpw[c*3+0],
                      fmaf(qcoord[qq*3+1], qpw[c*3+1],
                      fmaf(qcoord[qq*3+2], qpw[c*3+2], qpb[c])));
      qf[qv][c] = fmaxf(v, 0.0f);
    }
    __syncthreads();
    const int oc = t & 127, half = t >> 7;
    const float* wrow = in_w + (size_t)oc * CH;
    const float bia = in_b[oc];
    float acc[8];
    #pragma unroll
    for (int v = 0; v < 8; v++) acc[v] = bia;
    for (int c = 0; c < CH; c += 4) {
      const float4 w4 = *reinterpret_cast<const float4*>(wrow + c);
      #pragma unroll
      for (int v = 0; v < 8; v++) {
        const float4 g4 = *reinterpret_cast<const float4*>(&qf[half*8+v][c]);
        acc[v] = fmaf(g4.x, w4.x, fmaf(g4.y, w4.y, fmaf(g4.z, w4.z, fmaf(g4.w, w4.w, acc[v]))));
      }
    }
    #pragma unroll
    for (int v = 0; v < 8; v++) qout[(size_t)(qbase + half*8 + v)*CH + oc] = acc[v];
  }
}

// ---------------------------------------------------------------------------
// Kernel 1b: KV projection GEMM via MFMA bf16; head-major packed layout
// KVh[head][voxel][32]: shorts 0..15 = K-slice, 16..31 = V-slice (one line).
// ---------------------------------------------------------------------------
__global__ __launch_bounds__(256) void k_kv_gemm(
    const __hip_bfloat16* __restrict__ Gb, const __hip_bfloat16* __restrict__ Wb,
    const float* __restrict__ in_b,
    unsigned short* __restrict__ KVh) {
  __shared__ unsigned short ldsD[64][72];
  const int t = threadIdx.x;
  const int w = t >> 6;
  const int lane = t & 63;
  const int col = lane & 15;
  const int quad = lane >> 4;
  const int bx = blockIdx.x;
  const int v0 = (bx >> 2) * 64;
  const int cg = bx & 3;   // 0,1 = K ch 0..63 / 64..127; 2,3 = V

  const unsigned short* gRow =
      reinterpret_cast<const unsigned short*>(Gb) + (size_t)(v0 + w*16 + col)*CH + quad*8;
  short8 afrag[4];
  #pragma unroll
  for (int kq = 0; kq < 4; kq++)
    afrag[kq] = *reinterpret_cast<const short8*>(gRow + kq*32);

  float4v acc[4];
  #pragma unroll
  for (int j = 0; j < 4; j++) {
    const float bia = in_b[CH + cg*64 + j*16 + col];
    acc[j] = (float4v){bia, bia, bia, bia};
  }
  const unsigned short* wB = reinterpret_cast<const unsigned short*>(Wb);
  #pragma unroll
  for (int kq = 0; kq < 4; kq++) {
    #pragma unroll
    for (int j = 0; j < 4; j++) {
      const short8 bfrag = *reinterpret_cast<const short8*>(
          wB + (size_t)(cg*64 + j*16 + col)*CH + kq*32 + quad*8);
      acc[j] = __builtin_amdgcn_mfma_f32_16x16x32_bf16(afrag[kq], bfrag, acc[j], 0, 0, 0);
    }
  }
  #pragma unroll
  for (int j = 0; j < 4; j++)
    #pragma unroll
    for (int r = 0; r < 4; r++)
      ldsD[w*16 + quad*4 + r][j*16 + col] = f2bf(acc[j][r]);
  __syncthreads();
  const int row = t >> 2;
  const int cc  = (t & 3) * 16;
  const uint4 d0 = *reinterpret_cast<const uint4*>(&ldsD[row][cc]);
  const uint4 d1 = *reinterpret_cast<const uint4*>(&ldsD[row][cc+8]);
  const int head = (cg & 1) * 4 + (cc >> 4);
  const int isV  = cg >> 1;
  unsigned short* dst = KVh + ((size_t)head*NVOX + (v0 + row))*32 + isV*16;
  uint4* out = reinterpret_cast<uint4*>(dst);
  out[0] = d0; out[1] = d1;
}

// ---------------------------------------------------------------------------
// Kernel 3: attention — barrier-free, LDS-free, WASTE-FREE pair scheme.
// Block = (8q, 1h), 4 waves; quad of 4 lanes handles 12 keys as 6 (A,B) pairs.
// Lane r loads A-quarter r and B-quarter (r+2)&3 (one request per 64-B line).
// Score phase: every lane holds a K-half (r0/r1=A, r2/r3=B) — zero waste.
// ctx phase:   every lane holds a V-half (r0/r1=B, r2/r3=A) — zero waste.
// All reductions via butterfly shuffles. blockIdx.x = qg*8 + h (XCD pinning).
// ---------------------------------------------------------------------------
__global__ __launch_bounds__(256) void k_attn(
    const unsigned short* __restrict__ KVh,
    const float* __restrict__ qg, const int* __restrict__ kidx,
    float* __restrict__ ctxg) {
  const int t    = threadIdx.x;
  const int h    = blockIdx.x & 7;
  const int n0   = (blockIdx.x >> 3) * 8;
  const int w    = t >> 6;
  const int lane = t & 63;
  const int qh   = lane >> 5;        // which of the wave's 2 queries
  const int g    = (lane >> 2) & 7;  // key group: quad owns keys g+8m, m=0..11
  const int r    = lane & 3;         // role within quad
  const int q    = n0 + 2*w + qh;
  const bool loK = (r < 2);          // lane's score-class: true->A, false->B
  const unsigned short* KVbase = KVh + (size_t)h * NVOX * 32;

  // q half for scores: channels (r&1)*8 .. +7.
  const float* qrow = qg + (size_t)q*CH + h*16 + (r & 1)*8;
  const float4 qa = *reinterpret_cast<const float4*>(qrow);
  const float4 qb = *reinterpret_cast<const float4*>(qrow + 4);
#if HAVE_DOT2_BF16
  const unsigned qp0 = pack2(qa.x, qa.y), qp1 = pack2(qa.z, qa.w);
  const unsigned qp2 = pack2(qb.x, qb.y), qp3 = pack2(qb.z, qb.w);
#endif

  // Gather: 6 pairs; kS = my score-class K-half, kV = opposite-class V-half.
  const int krow = q*KK + g;
  uint4 kS[6], kV[6];
  unsigned mA = 0, mB = 0;
  #pragma unroll
  for (int i = 0; i < 6; i++) {
    const int jA0 = kidx[krow + 16*i];
    const int jB0 = kidx[krow + 16*i + 8];
    mA |= (unsigned)(jA0 < 0) << i;
    mB |= (unsigned)(jB0 < 0) << i;
    const int jA = (jA0 < 0) ? 0 : jA0;   // clamp like reference
    const int jB = (jB0 < 0) ? 0 : jB0;
    const int jSc = loK ? jA : jB;
    const int jVc = loK ? jB : jA;
    kS[i] = *reinterpret_cast<const uint4*>(KVbase + (size_t)jSc*32 + (r & 1)*8);
    kV[i] = *reinterpret_cast<const uint4*>(KVbase + (size_t)jVc*32 + 16 + (r & 1)*8);
  }
  const unsigned mS = loK ? mA : mB;
  // Scores: 8-ch partial dot, combined across the r-pair by shfl_xor(1).
  float sv[6];
  #pragma unroll
  for (int i = 0; i < 6; i++) {
    const uint4 kv = kS[i];
    float s = 0.0f;
#if HAVE_DOT2_BF16
    s = dot2bf(kv.x, qp0, s); s = dot2bf(kv.y, qp1, s);
    s = dot2bf(kv.z, qp2, s); s = dot2bf(kv.w, qp3, s);
#else
    s = fmaf(qa.x, bflo(kv.x), s); s = fmaf(qa.y, bfhi(kv.x), s);
    s = fmaf(qa.z, bflo(kv.y), s); s = fmaf(qa.w, bfhi(kv.y), s);
    s = fmaf(qb.x, bflo(kv.z), s); s = fmaf(qb.y, bfhi(kv.z), s);
    s = fmaf(qb.z, bflo(kv.w), s); s = fmaf(qb.w, bfhi(kv.w), s);
#endif
    s += __shfl_xor(s, 1);           // r0+r1 = full A dot; r2+r3 = full B dot
    sv[i] = ((mS >> i) & 1) ? -1e9f : s * 0.25f;   // 1/sqrt(16)
  }
  // Softmax over the query's 96 keys. r-pairs hold duplicate values, so the
  // xor2 (class merge) + xor4/8/16 (quad merge) chain stays exact.
  float mx = sv[0];
  #pragma unroll
  for (int i = 1; i < 6; i++) mx = fmaxf(mx, sv[i]);
  mx = fmaxf(mx, __shfl_xor(mx, 2));
  mx = fmaxf(mx, __shfl_xor(mx, 4));
  mx = fmaxf(mx, __shfl_xor(mx, 8));
  mx = fmaxf(mx, __shfl_xor(mx, 16));
  float sum = 0.0f;
  #pragma unroll
  for (int i = 0; i < 6; i++) { sv[i] = __expf(sv[i] - mx); sum += sv[i]; }
  sum += __shfl_xor(sum, 2);
  sum += __shfl_xor(sum, 4);
  sum += __shfl_xor(sum, 8);
  sum += __shfl_xor(sum, 16);
  const float inv = 1.0f / sum;      // masked keys: exp underflows to exact 0
  #pragma unroll
  for (int i = 0; i < 6; i++) sv[i] *= inv;
  // ctx: lane accumulates its V-half of the OPPOSITE class; weight fetched
  // from the class-owner lane (r0 holds A weights, r2 holds B weights).
  const int qlane = lane & ~3;
  const int wsrc  = qlane | (loK ? 2 : 0);
  float acc[8] = {0,0,0,0,0,0,0,0};
  #pragma unroll
  for (int i = 0; i < 6; i++) {
    const float wg = __shfl(sv[i], wsrc);
    const uint4 kv = kV[i];
    acc[0] = fmaf(wg, bflo(kv.x), acc[0]); acc[1] = fmaf(wg, bfhi(kv.x), acc[1]);
    acc[2] = fmaf(wg, bflo(kv.y), acc[2]); acc[3] = fmaf(wg, bfhi(kv.y), acc[3]);
    acc[4] = fmaf(wg, bflo(kv.z), acc[4]); acc[5] = fmaf(wg, bfhi(kv.z), acc[5]);
    acc[6] = fmaf(wg, bflo(kv.w), acc[6]); acc[7] = fmaf(wg, bfhi(kv.w), acc[7]);
  }
  // Reduce: xor2 merges classes (r0+r2 -> ch half r&1), xor4/8/16 merge quads.
  #pragma unroll
  for (int u = 0; u < 8; u++) {
    acc[u] += __shfl_xor(acc[u], 2);
    acc[u] += __shfl_xor(acc[u], 4);
    acc[u] += __shfl_xor(acc[u], 8);
    acc[u] += __shfl_xor(acc[u], 16);
  }
  // Store: g==0, r0 writes ch 0-7, r1 writes ch 8-15 (8 floats each).
  if (g == 0 && r < 2) {
    float* dst = ctxg + (size_t)q*CH + h*16 + r*8;
    *reinterpret_cast<float4*>(dst)     = make_float4(acc[0], acc[1], acc[2], acc[3]);
    *reinterpret_cast<float4*>(dst + 4) = make_float4(acc[4], acc[5], acc[6], acc[7]);
  }
}

// ---------------------------------------------------------------------------
// Kernel 4: epilogue via MFMA bf16 (unchanged).
// ---------------------------------------------------------------------------
__global__ __launch_bounds__(256) void k_epi(
    const float* __restrict__ ctxg, const __hip_bfloat16* __restrict__ Eb,
    const float* __restrict__ ob,
    const float* __restrict__ n2g, const float* __restrict__ n2b,
    const float* __restrict__ l1b, const float* __restrict__ l2b,
    const float* __restrict__ fb,
    float* __restrict__ outp) {
  __shared__ unsigned short csb[16][136];
  __shared__ float attnS[16][132];
  __shared__ unsigned short hb[16][136];
  __shared__ unsigned short a1b[16][264];
  __shared__ unsigned short xb[16][136];
  const unsigned short* owb  = reinterpret_cast<const unsigned short*>(Eb);
  const unsigned short* l1wb = owb + 16384;
  const unsigned short* l2wb = owb + 49152;
  const unsigned short* fwb  = owb + 81920;

  const int t = threadIdx.x;
  const int w = t >> 6;
  const int lane = t & 63;
  const int col = lane & 15;
  const int quad = lane >> 4;
  const int qbase = blockIdx.x * 16;

  {
    const int e = t * 8;
    const int row = e >> 7, cc = e & 127;
    const float4* src = reinterpret_cast<const float4*>(ctxg + (size_t)(qbase+row)*CH + cc);
    const float4 x0 = src[0], x1 = src[1];
    *reinterpret_cast<uint4*>(&csb[row][cc]) =
        make_uint4(pack2(x0.x,x0.y), pack2(x0.z,x0.w), pack2(x1.x,x1.y), pack2(x1.z,x1.w));
  }
  __syncthreads();
  {
    short8 af[4];
    #pragma unroll
    for (int kq = 0; kq < 4; kq++)
      af[kq] = *reinterpret_cast<const short8*>(&csb[col][quad*8 + kq*32]);
    #pragma unroll
    for (int j = 0; j < 2; j++) {
      const int n0 = w*32 + j*16;
      const float bia = ob[n0 + col];
      float4v acc = (float4v){bia, bia, bia, bia};
      #pragma unroll
      for (int kq = 0; kq < 4; kq++) {
        const short8 bf = *reinterpret_cast<const short8*>(
            owb + (size_t)(n0 + col)*CH + kq*32 + quad*8);
        acc = __builtin_amdgcn_mfma_f32_16x16x32_bf16(af[kq], bf, acc, 0, 0, 0);
      }
      #pragma unroll
      for (int r = 0; r < 4; r++) attnS[quad*4 + r][n0 + col] = acc[r];
    }
  }
  __syncthreads();
  {
    const int row = t >> 4, l = t & 15;
    float s = 0.0f, ss = 0.0f;
    #pragma unroll
    for (int c = l; c < CH; c += 16) { const float x = attnS[row][c]; s += x; ss += x*x; }
    #pragma unroll
    for (int m = 8; m >= 1; m >>= 1) { s += __shfl_xor(s, m); ss += __shfl_xor(ss, m); }
    const float mean = s * (1.0f/CH);
    const float var  = ss * (1.0f/CH) - mean*mean;
    const float rstd = 1.0f / sqrtf(var + 1e-5f);
    #pragma unroll
    for (int c = l; c < CH; c += 16)
      hb[row][c] = f2bf((attnS[row][c] - mean) * rstd * n2g[c] + n2b[c]);
  }
  __syncthreads();
  {
    short8 af[4];
    #pragma unroll
    for (int kq = 0; kq < 4; kq++)
      af[kq] = *reinterpret_cast<const short8*>(&hb[col][quad*8 + kq*32]);
    #pragma unroll
    for (int j = 0; j < 4; j++) {
      const int n0 = w*64 + j*16;
      const float bia = l1b[n0 + col];
      float4v acc = (float4v){bia, bia, bia, bia};
      #pragma unroll
      for (int kq = 0; kq < 4; kq++) {
        const short8 bf = *reinterpret_cast<const short8*>(
            l1wb + (size_t)(n0 + col)*CH + kq*32 + quad*8);
        acc = __builtin_amdgcn_mfma_f32_16x16x32_bf16(af[kq], bf, acc, 0, 0, 0);
      }
      #pragma unroll
      for (int r = 0; r < 4; r++)
        a1b[quad*4 + r][n0 + col] = f2bf(fmaxf(acc[r], 0.0f));
    }
  }
  __syncthreads();
  {
    short8 af[8];
    #pragma unroll
    for (int kq = 0; kq < 8; kq++)
      af[kq] = *reinterpret_cast<const short8*>(&a1b[col][quad*8 + kq*32]);
    #pragma unroll
    for (int j = 0; j < 2; j++) {
      const int n0 = w*32 + j*16;
      const float bia = l2b[n0 + col];
      float4v acc = (float4v){bia, bia, bia, bia};
      #pragma unroll
      for (int kq = 0; kq < 8; kq++) {
        const short8 bf = *reinterpret_cast<const short8*>(
            l2wb + (size_t)(n0 + col)*FFD + kq*32 + quad*8);
        acc = __builtin_amdgcn_mfma_f32_16x16x32_bf16(af[kq], bf, acc, 0, 0, 0);
      }
      #pragma unroll
      for (int r = 0; r < 4; r++)
        xb[quad*4 + r][n0 + col] = f2bf(acc[r] + attnS[quad*4 + r][n0 + col]);
    }
  }
  __syncthreads();
  {
    short8 af[4];
    #pragma unroll
    for (int kq = 0; kq < 4; kq++)
      af[kq] = *reinterpret_cast<const short8*>(&xb[col][quad*8 + kq*32]);
    #pragma unroll
    for (int j = 0; j < 2; j++) {
      const int n0 = w*32 + j*16;
      const float bia = fb[n0 + col];
      float4v acc = (float4v){bia, bia, bia, bia};
      #pragma unroll
      for (int kq = 0; kq < 4; kq++) {
        const short8 bf = *reinterpret_cast<const short8*>(
            fwb + (size_t)(n0 + col)*CH + kq*32 + quad*8);
        acc = __builtin_amdgcn_mfma_f32_16x16x32_bf16(af[kq], bf, acc, 0, 0, 0);
      }
      #pragma unroll
      for (int r = 0; r < 4; r++)
        outp[(size_t)(qbase + quad*4 + r)*CH + n0 + col] = fmaxf(acc[r], 0.0f);
    }
  }
}

// ---------------------------------------------------------------------------
extern "C" void kernel_launch(void* const* d_in, const int* in_sizes, int n_in,
                              void* d_out, int out_size, void* d_ws, size_t ws_size,
                              hipStream_t stream) {
  const float* vfeat  = (const float*)d_in[0];
  const float* vcoord = (const float*)d_in[1];
  const float* qcoord = (const float*)d_in[2];
  const int*   kidx   = (const int*)  d_in[3];
  const float* n1g    = (const float*)d_in[4];
  const float* n1b    = (const float*)d_in[5];
  const float* qpw    = (const float*)d_in[6];
  const float* qpb    = (const float*)d_in[7];
  const float* kpw    = (const float*)d_in[8];
  const float* kpb    = (const float*)d_in[9];
  const float* in_w   = (const float*)d_in[10];
  const float* in_b   = (const float*)d_in[11];
  const float* out_w  = (const float*)d_in[12];
  const float* out_b  = (const float*)d_in[13];
  const float* n2g    = (const float*)d_in[14];
  const float* n2b    = (const float*)d_in[15];
  const float* l1w    = (const float*)d_in[16];
  const float* l1b    = (const float*)d_in[17];
  const float* l2w    = (const float*)d_in[18];
  const float* l2b    = (const float*)d_in[19];
  const float* fw     = (const float*)d_in[20];
  const float* fb     = (const float*)d_in[21];
  float* out = (float*)d_out;

  unsigned short* KVh = (unsigned short*)d_ws;          // 8*NVOX*32 shorts (20.5 MB)
  __hip_bfloat16* Gb = (__hip_bfloat16*)(KVh + (size_t)8*NVOX*32);  // NVOX*CH bf16
  __hip_bfloat16* Wb = Gb + (size_t)NVOX*CH;            // 256*CH bf16
  __hip_bfloat16* Eb = Wb + (size_t)2*CH*CH;            // 98304 bf16 epi weights
  float* qb = (float*)(Eb + 98304);                     // NQRY*CH f32
  float* cx = qb + (size_t)NQRY*CH;                     // NQRY*CH f32

  k_prep   <<<NVOX/16 + 32 + NQRY/16, 256, 0, stream>>>(
      vfeat, vcoord, n1g, n1b, kpw, kpb, in_w, in_b,
      out_w, l1w, l2w, fw, qcoord, qpw, qpb, Gb, Wb, Eb, qb);
  k_kv_gemm<<<(NVOX/64)*4, 256, 0, stream>>>(Gb, Wb, in_b, KVh);
  k_attn   <<<(NQRY/8)*8, 256, 0, stream>>>(KVh, qb, kidx, cx);
  k_epi    <<<NQRY/16, 256, 0, stream>>>(cx, Eb, out_b, n2g, n2b, l1b, l2b, fb, out);
}

// Round 9
// 211.158 us; speedup vs baseline: 1.0464x; 1.0464x over previous
//
#include <hip/hip_runtime.h>
#include <hip/hip_bf16.h>
#include <math.h>

// Problem constants (fixed by reference).
constexpr int NVOX = 40000;
constexpr int NQRY = 8192;
constexpr int KK   = 96;
constexpr int CH   = 128;
constexpr int FFD  = 256;

typedef __attribute__((ext_vector_type(8))) short short8;
typedef __attribute__((ext_vector_type(4))) float float4v;

__device__ inline float bflo(unsigned u) { return __uint_as_float(u << 16); }
__device__ inline float bfhi(unsigned u) { return __uint_as_float(u & 0xffff0000u); }
__device__ inline unsigned short f2bf(float x) {
  union { float f; unsigned u; } a; a.f = x;
  const unsigned r = a.u + 0x7fffu + ((a.u >> 16) & 1u);  // round-to-nearest-even
  return (unsigned short)(r >> 16);
}
__device__ inline unsigned pack2(float lo, float hi) {
  return (unsigned)f2bf(lo) | ((unsigned)f2bf(hi) << 16);
}

// ---------------------------------------------------------------------------
// Kernel 1: prep (merged) —
//  blocks [0, NVOX/16):         per-voxel LN + relu(key-pos) -> Gb bf16
//  blocks [NVOX/16, +8):        Wkv -> Wb bf16
//  blocks [NVOX/16+8, +24):     epilogue weights -> Eb bf16
//  blocks [NVOX/16+32, +512):   q = relu(qc@q_pos_w.T+b) @ wq.T + bq -> qb f32
// ---------------------------------------------------------------------------
__global__ __launch_bounds__(256) void k_prep(
    const float* __restrict__ vfeat, const float* __restrict__ vcoord,
    const float* __restrict__ n1g, const float* __restrict__ n1b,
    const float* __restrict__ kpw, const float* __restrict__ kpb,
    const float* __restrict__ in_w, const float* __restrict__ in_b,
    const float* __restrict__ ow, const float* __restrict__ l1w,
    const float* __restrict__ l2w, const float* __restrict__ fw,
    const float* __restrict__ qcoord,
    const float* __restrict__ qpw, const float* __restrict__ qpb,
    __hip_bfloat16* __restrict__ Gb, __hip_bfloat16* __restrict__ Wb,
    __hip_bfloat16* __restrict__ Eb, float* __restrict__ qout) {
  const int b = blockIdx.x;
  const int t = threadIdx.x;
  if (b < NVOX/16) {
    const int vloc = t >> 4;
    const int l    = t & 15;
    const int j = b * 16 + vloc;
    const float4* vrow = reinterpret_cast<const float4*>(vfeat + (size_t)j * CH);
    const float4 x0 = vrow[l*2], x1 = vrow[l*2+1];
    float s  = x0.x+x0.y+x0.z+x0.w + x1.x+x1.y+x1.z+x1.w;
    float ss = x0.x*x0.x+x0.y*x0.y+x0.z*x0.z+x0.w*x0.w
             + x1.x*x1.x+x1.y*x1.y+x1.z*x1.z+x1.w*x1.w;
    #pragma unroll
    for (int m = 8; m >= 1; m >>= 1) { s += __shfl_xor(s, m); ss += __shfl_xor(ss, m); }
    const float mean = s * (1.0f/CH);
    const float var  = ss * (1.0f/CH) - mean*mean;
    const float rstd = 1.0f / sqrtf(var + 1e-5f);
    const float c0 = vcoord[j*3+0], c1 = vcoord[j*3+1], c2 = vcoord[j*3+2];
    const float xv[8] = {x0.x,x0.y,x0.z,x0.w,x1.x,x1.y,x1.z,x1.w};
    float gv[8];
    #pragma unroll
    for (int u = 0; u < 8; u++) {
      const int c = l*8 + u;
      const float vf = (xv[u] - mean) * rstd * n1g[c] + n1b[c];
      const float kp = fmaf(c0, kpw[c*3+0], fmaf(c1, kpw[c*3+1], fmaf(c2, kpw[c*3+2], kpb[c])));
      gv[u] = vf + fmaxf(kp, 0.0f);
    }
    const uint4 pk = make_uint4(pack2(gv[0],gv[1]), pack2(gv[2],gv[3]),
                                pack2(gv[4],gv[5]), pack2(gv[6],gv[7]));
    *reinterpret_cast<uint4*>(Gb + (size_t)j*CH + l*8) = pk;
  } else if (b < NVOX/16 + 32) {
    const int idx = b - NVOX/16;
    const float* src;
    __hip_bfloat16* dst;
    if (idx < 8) {
      const int e = (idx * 256 + t) * 16;
      src = in_w + (size_t)CH*CH + e;
      dst = Wb + e;
    } else {
      const int f = ((idx - 8) * 256 + t) * 16;   // 0..98303
      dst = Eb + f;
      if      (f < 16384) src = ow  + f;
      else if (f < 49152) src = l1w + (f - 16384);
      else if (f < 81920) src = l2w + (f - 49152);
      else                src = fw  + (f - 81920);
    }
    float v[16];
    #pragma unroll
    for (int u = 0; u < 4; u++) {
      const float4 fq = *reinterpret_cast<const float4*>(src + u*4);
      v[u*4+0]=fq.x; v[u*4+1]=fq.y; v[u*4+2]=fq.z; v[u*4+3]=fq.w;
    }
    uint4* o = reinterpret_cast<uint4*>(dst);
    o[0] = make_uint4(pack2(v[0],v[1]), pack2(v[2],v[3]),
                      pack2(v[4],v[5]), pack2(v[6],v[7]));
    o[1] = make_uint4(pack2(v[8],v[9]), pack2(v[10],v[11]),
                      pack2(v[12],v[13]), pack2(v[14],v[15]));
  } else {
    // q projection: 16 queries per block.
    __shared__ float qf[16][CH];
    const int qbase = (b - (NVOX/16 + 32)) * 16;
    #pragma unroll
    for (int i = 0; i < 8; i++) {
      const int e = t + 256*i;
      const int qv = e >> 7, c = e & 127;
      const int qq = qbase + qv;
      const float v = fmaf(qcoord[qq*3+0], qpw[c*3+0],
                      fmaf(qcoord[qq*3+1], qpw[c*3+1],
                      fmaf(qcoord[qq*3+2], qpw[c*3+2], qpb[c])));
      qf[qv][c] = fmaxf(v, 0.0f);
    }
    __syncthreads();
    const int oc = t & 127, half = t >> 7;
    const float* wrow = in_w + (size_t)oc * CH;
    const float bia = in_b[oc];
    float acc[8];
    #pragma unroll
    for (int v = 0; v < 8; v++) acc[v] = bia;
    for (int c = 0; c < CH; c += 4) {
      const float4 w4 = *reinterpret_cast<const float4*>(wrow + c);
      #pragma unroll
      for (int v = 0; v < 8; v++) {
        const float4 g4 = *reinterpret_cast<const float4*>(&qf[half*8+v][c]);
        acc[v] = fmaf(g4.x, w4.x, fmaf(g4.y, w4.y, fmaf(g4.z, w4.z, fmaf(g4.w, w4.w, acc[v]))));
      }
    }
    #pragma unroll
    for (int v = 0; v < 8; v++) qout[(size_t)(qbase + half*8 + v)*CH + oc] = acc[v];
  }
}

// ---------------------------------------------------------------------------
// Kernel 1b: KV projection GEMM via MFMA bf16; head-major packed layout
// KVh[head][voxel][32]: shorts 0..15 = K-slice, 16..31 = V-slice (one line).
// ---------------------------------------------------------------------------
__global__ __launch_bounds__(256) void k_kv_gemm(
    const __hip_bfloat16* __restrict__ Gb, const __hip_bfloat16* __restrict__ Wb,
    const float* __restrict__ in_b,
    unsigned short* __restrict__ KVh) {
  __shared__ unsigned short ldsD[64][72];
  const int t = threadIdx.x;
  const int w = t >> 6;
  const int lane = t & 63;
  const int col = lane & 15;
  const int quad = lane >> 4;
  const int bx = blockIdx.x;
  const int v0 = (bx >> 2) * 64;
  const int cg = bx & 3;   // 0,1 = K ch 0..63 / 64..127; 2,3 = V

  const unsigned short* gRow =
      reinterpret_cast<const unsigned short*>(Gb) + (size_t)(v0 + w*16 + col)*CH + quad*8;
  short8 afrag[4];
  #pragma unroll
  for (int kq = 0; kq < 4; kq++)
    afrag[kq] = *reinterpret_cast<const short8*>(gRow + kq*32);

  float4v acc[4];
  #pragma unroll
  for (int j = 0; j < 4; j++) {
    const float bia = in_b[CH + cg*64 + j*16 + col];
    acc[j] = (float4v){bia, bia, bia, bia};
  }
  const unsigned short* wB = reinterpret_cast<const unsigned short*>(Wb);
  #pragma unroll
  for (int kq = 0; kq < 4; kq++) {
    #pragma unroll
    for (int j = 0; j < 4; j++) {
      const short8 bfrag = *reinterpret_cast<const short8*>(
          wB + (size_t)(cg*64 + j*16 + col)*CH + kq*32 + quad*8);
      acc[j] = __builtin_amdgcn_mfma_f32_16x16x32_bf16(afrag[kq], bfrag, acc[j], 0, 0, 0);
    }
  }
  #pragma unroll
  for (int j = 0; j < 4; j++)
    #pragma unroll
    for (int r = 0; r < 4; r++)
      ldsD[w*16 + quad*4 + r][j*16 + col] = f2bf(acc[j][r]);
  __syncthreads();
  const int row = t >> 2;
  const int cc  = (t & 3) * 16;
  const uint4 d0 = *reinterpret_cast<const uint4*>(&ldsD[row][cc]);
  const uint4 d1 = *reinterpret_cast<const uint4*>(&ldsD[row][cc+8]);
  const int head = (cg & 1) * 4 + (cc >> 4);
  const int isV  = cg >> 1;
  unsigned short* dst = KVh + ((size_t)head*NVOX + (v0 + row))*32 + isV*16;
  uint4* out = reinterpret_cast<uint4*>(dst);
  out[0] = d0; out[1] = d1;
}

// ---------------------------------------------------------------------------
// Kernel 2b: k_warm — head-pinned L2 prefetch. Blocks 0..999: b&7 = head
// (same %8 XCD mapping as k_attn), each streams 1/125 of that head's 2.56 MB
// KVh slice into the local XCD L2. Blocks 1000..1111: stream kidx (3 MB) +
// qg (4 MB) to warm L3. XOR-consume + impossible-value store prevents DCE.
// ---------------------------------------------------------------------------
__global__ __launch_bounds__(256) void k_warm(
    const uint4* __restrict__ kv4, const uint4* __restrict__ kidx4,
    const uint4* __restrict__ qg4, unsigned* __restrict__ sink) {
  const int b = blockIdx.x;
  const int t = threadIdx.x;
  unsigned acc = 0;
  if (b < 1000) {
    const int h = b & 7, chunk = b >> 3;          // chunk 0..124
    const uint4* p = kv4 + (size_t)h*160000 + (size_t)chunk*1280 + t;
    #pragma unroll
    for (int i = 0; i < 5; i++) {
      const uint4 v = p[i*256];
      acc ^= v.x ^ v.y ^ v.z ^ v.w;
    }
  } else {
    const int off = (b - 1000) * 4096 + t;        // 112 blocks x 4096 uint4
    #pragma unroll
    for (int i = 0; i < 16; i++) {
      const int idx = off + i*256;
      const uint4 v = (idx < 196608) ? kidx4[idx] : qg4[idx - 196608];
      acc ^= v.x ^ v.y ^ v.z ^ v.w;
    }
  }
  if (acc == 0xDEADBEEFu) sink[0] = acc;          // never in practice; keeps loads
}

// ---------------------------------------------------------------------------
// Kernel 3: attention (round-6 proven-fastest structure). Block = (8q, 1h);
// blockIdx.x = qg*8 + h so round-robin XCD dispatch pins head<->XCD.
// 4 lanes per (q,k): each loads dwordx4 -> full 64-B line in ONE request.
// r0/r1 = K halves (score via shfl_xor(.,1)); r2/r3 = V halves, kept in
// registers across softmax, accumulated into ctx locally, reduced via LDS.
// ---------------------------------------------------------------------------
__global__ __launch_bounds__(256) void k_attn(
    const unsigned short* __restrict__ KVh,
    const float* __restrict__ qg, const int* __restrict__ kidx,
    float* __restrict__ ctxg) {
  __shared__ float qs[8][16];
  __shared__ float sc[8*104];     // stride 104: conflict-free softmax/ctx reads
  __shared__ float red[128][9];   // slot-padded ctx partials
  __shared__ float rden[8];
  const int t    = threadIdx.x;
  const int h    = blockIdx.x & 7;
  const int n0   = (blockIdx.x >> 3) * 8;
  const int w    = t >> 6;
  const int lane = t & 63;
  const int quad = lane >> 2;     // 0..15
  const int r    = lane & 3;      // lane role within quad
  const int qh   = quad >> 3;     // 0/1: which of the wave's 2 queries
  const int g    = quad & 7;      // key slot group: keys g, g+8, ..., g+88
  const int q_l  = 2*w + qh;      // block-local query 0..7
  const unsigned short* KVbase = KVh + (size_t)h * NVOX * 32;

  if (t < 128) {
    const int q = t >> 4, d = t & 15;
    qs[q][d] = qg[(size_t)(n0 + q)*CH + h*16 + d];
  }
  // Loads: 12 keys per quad; each lane fetches its 16-B quarter of the line.
  unsigned msk = 0;
  uint4 kvbuf[12];
  const int krow = (n0 + q_l)*KK + g;
  #pragma unroll
  for (int it = 0; it < 12; it++) {
    const int j0 = kidx[krow + it*8];
    msk |= (unsigned)(j0 < 0) << it;
    const int j = (j0 < 0) ? 0 : j0;   // clamp like reference
    kvbuf[it] = *reinterpret_cast<const uint4*>(KVbase + (size_t)j*32 + r*8);
  }
  __syncthreads();
  // Scores: r0/r1 lanes hold K halves; q half selected by r&1.
  const float4 qa = *reinterpret_cast<const float4*>(&qs[q_l][(r & 1)*8]);
  const float4 qb = *reinterpret_cast<const float4*>(&qs[q_l][(r & 1)*8 + 4]);
  #pragma unroll
  for (int it = 0; it < 12; it++) {
    const uint4 kv = kvbuf[it];
    float s = 0.0f;
    s = fmaf(qa.x, bflo(kv.x), s); s = fmaf(qa.y, bfhi(kv.x), s);
    s = fmaf(qa.z, bflo(kv.y), s); s = fmaf(qa.w, bfhi(kv.y), s);
    s = fmaf(qb.x, bflo(kv.z), s); s = fmaf(qb.y, bfhi(kv.z), s);
    s = fmaf(qb.z, bflo(kv.w), s); s = fmaf(qb.w, bfhi(kv.w), s);
    s += __shfl_xor(s, 1);          // r0+r1 (K full dot); r2+r3 garbage unused
    if (r == 0)
      sc[q_l*104 + g + it*8] = ((msk >> it) & 1) ? -1e9f : s * 0.25f;
  }
  __syncthreads();
  // Softmax per query: 16 lanes over 96 keys.
  if (t < 128) {
    const int q = t >> 4, l = t & 15;
    float mx = -3e38f;
    #pragma unroll
    for (int k = l; k < KK; k += 16) mx = fmaxf(mx, sc[q*104 + k]);
    #pragma unroll
    for (int m = 8; m >= 1; m >>= 1) mx = fmaxf(mx, __shfl_xor(mx, m));
    float sum = 0.0f;
    #pragma unroll
    for (int k = l; k < KK; k += 16) {
      const float p = __expf(sc[q*104 + k] - mx);   // masked -> exactly 0
      sc[q*104 + k] = p;
      sum += p;
    }
    #pragma unroll
    for (int m = 8; m >= 1; m >>= 1) sum += __shfl_xor(sum, m);
    if (l == 0) rden[q] = 1.0f / sum;
  }
  __syncthreads();
  // ctx: r2/r3 lanes accumulate their V half over their 12 keys.
  {
    float acc[8] = {0,0,0,0,0,0,0,0};
    #pragma unroll
    for (int it = 0; it < 12; it++) {
      const float wg = sc[q_l*104 + g + it*8];   // broadcast within quad
      const uint4 kv = kvbuf[it];
      acc[0] = fmaf(wg, bflo(kv.x), acc[0]); acc[1] = fmaf(wg, bfhi(kv.x), acc[1]);
      acc[2] = fmaf(wg, bflo(kv.y), acc[2]); acc[3] = fmaf(wg, bfhi(kv.y), acc[3]);
      acc[4] = fmaf(wg, bflo(kv.z), acc[4]); acc[5] = fmaf(wg, bfhi(kv.z), acc[5]);
      acc[6] = fmaf(wg, bflo(kv.w), acc[6]); acc[7] = fmaf(wg, bfhi(kv.w), acc[7]);
    }
    if (r >= 2) {
      const int slot = q_l*16 + g*2 + (r - 2);   // 0..127
      #pragma unroll
      for (int u = 0; u < 8; u++) red[slot][u] = acc[u];
    }
  }
  __syncthreads();
  // Reduce 8 slot-groups per (query, channel) and store.
  if (t < 128) {
    const int q = t >> 4, d = t & 15;
    const int half = d >> 3, u = d & 7;
    float s = 0.0f;
    #pragma unroll
    for (int gg = 0; gg < 8; gg++) s += red[q*16 + gg*2 + half][u];
    ctxg[(size_t)(n0 + q)*CH + h*16 + d] = s * rden[q];
  }
}

// ---------------------------------------------------------------------------
// Kernel 4: epilogue via MFMA bf16 (unchanged).
// ---------------------------------------------------------------------------
__global__ __launch_bounds__(256) void k_epi(
    const float* __restrict__ ctxg, const __hip_bfloat16* __restrict__ Eb,
    const float* __restrict__ ob,
    const float* __restrict__ n2g, const float* __restrict__ n2b,
    const float* __restrict__ l1b, const float* __restrict__ l2b,
    const float* __restrict__ fb,
    float* __restrict__ outp) {
  __shared__ unsigned short csb[16][136];
  __shared__ float attnS[16][132];
  __shared__ unsigned short hb[16][136];
  __shared__ unsigned short a1b[16][264];
  __shared__ unsigned short xb[16][136];
  const unsigned short* owb  = reinterpret_cast<const unsigned short*>(Eb);
  const unsigned short* l1wb = owb + 16384;
  const unsigned short* l2wb = owb + 49152;
  const unsigned short* fwb  = owb + 81920;

  const int t = threadIdx.x;
  const int w = t >> 6;
  const int lane = t & 63;
  const int col = lane & 15;
  const int quad = lane >> 4;
  const int qbase = blockIdx.x * 16;

  {
    const int e = t * 8;
    const int row = e >> 7, cc = e & 127;
    const float4* src = reinterpret_cast<const float4*>(ctxg + (size_t)(qbase+row)*CH + cc);
    const float4 x0 = src[0], x1 = src[1];
    *reinterpret_cast<uint4*>(&csb[row][cc]) =
        make_uint4(pack2(x0.x,x0.y), pack2(x0.z,x0.w), pack2(x1.x,x1.y), pack2(x1.z,x1.w));
  }
  __syncthreads();
  {
    short8 af[4];
    #pragma unroll
    for (int kq = 0; kq < 4; kq++)
      af[kq] = *reinterpret_cast<const short8*>(&csb[col][quad*8 + kq*32]);
    #pragma unroll
    for (int j = 0; j < 2; j++) {
      const int n0 = w*32 + j*16;
      const float bia = ob[n0 + col];
      float4v acc = (float4v){bia, bia, bia, bia};
      #pragma unroll
      for (int kq = 0; kq < 4; kq++) {
        const short8 bf = *reinterpret_cast<const short8*>(
            owb + (size_t)(n0 + col)*CH + kq*32 + quad*8);
        acc = __builtin_amdgcn_mfma_f32_16x16x32_bf16(af[kq], bf, acc, 0, 0, 0);
      }
      #pragma unroll
      for (int r = 0; r < 4; r++) attnS[quad*4 + r][n0 + col] = acc[r];
    }
  }
  __syncthreads();
  {
    const int row = t >> 4, l = t & 15;
    float s = 0.0f, ss = 0.0f;
    #pragma unroll
    for (int c = l; c < CH; c += 16) { const float x = attnS[row][c]; s += x; ss += x*x; }
    #pragma unroll
    for (int m = 8; m >= 1; m >>= 1) { s += __shfl_xor(s, m); ss += __shfl_xor(ss, m); }
    const float mean = s * (1.0f/CH);
    const float var  = ss * (1.0f/CH) - mean*mean;
    const float rstd = 1.0f / sqrtf(var + 1e-5f);
    #pragma unroll
    for (int c = l; c < CH; c += 16)
      hb[row][c] = f2bf((attnS[row][c] - mean) * rstd * n2g[c] + n2b[c]);
  }
  __syncthreads();
  {
    short8 af[4];
    #pragma unroll
    for (int kq = 0; kq < 4; kq++)
      af[kq] = *reinterpret_cast<const short8*>(&hb[col][quad*8 + kq*32]);
    #pragma unroll
    for (int j = 0; j < 4; j++) {
      const int n0 = w*64 + j*16;
      const float bia = l1b[n0 + col];
      float4v acc = (float4v){bia, bia, bia, bia};
      #pragma unroll
      for (int kq = 0; kq < 4; kq++) {
        const short8 bf = *reinterpret_cast<const short8*>(
            l1wb + (size_t)(n0 + col)*CH + kq*32 + quad*8);
        acc = __builtin_amdgcn_mfma_f32_16x16x32_bf16(af[kq], bf, acc, 0, 0, 0);
      }
      #pragma unroll
      for (int r = 0; r < 4; r++)
        a1b[quad*4 + r][n0 + col] = f2bf(fmaxf(acc[r], 0.0f));
    }
  }
  __syncthreads();
  {
    short8 af[8];
    #pragma unroll
    for (int kq = 0; kq < 8; kq++)
      af[kq] = *reinterpret_cast<const short8*>(&a1b[col][quad*8 + kq*32]);
    #pragma unroll
    for (int j = 0; j < 2; j++) {
      const int n0 = w*32 + j*16;
      const float bia = l2b[n0 + col];
      float4v acc = (float4v){bia, bia, bia, bia};
      #pragma unroll
      for (int kq = 0; kq < 8; kq++) {
        const short8 bf = *reinterpret_cast<const short8*>(
            l2wb + (size_t)(n0 + col)*FFD + kq*32 + quad*8);
        acc = __builtin_amdgcn_mfma_f32_16x16x32_bf16(af[kq], bf, acc, 0, 0, 0);
      }
      #pragma unroll
      for (int r = 0; r < 4; r++)
        xb[quad*4 + r][n0 + col] = f2bf(acc[r] + attnS[quad*4 + r][n0 + col]);
    }
  }
  __syncthreads();
  {
    short8 af[4];
    #pragma unroll
    for (int kq = 0; kq < 4; kq++)
      af[kq] = *reinterpret_cast<const short8*>(&xb[col][quad*8 + kq*32]);
    #pragma unroll
    for (int j = 0; j < 2; j++) {
      const int n0 = w*32 + j*16;
      const float bia = fb[n0 + col];
      float4v acc = (float4v){bia, bia, bia, bia};
      #pragma unroll
      for (int kq = 0; kq < 4; kq++) {
        const short8 bf = *reinterpret_cast<const short8*>(
            fwb + (size_t)(n0 + col)*CH + kq*32 + quad*8);
        acc = __builtin_amdgcn_mfma_f32_16x16x32_bf16(af[kq], bf, acc, 0, 0, 0);
      }
      #pragma unroll
      for (int r = 0; r < 4; r++)
        outp[(size_t)(qbase + quad*4 + r)*CH + n0 + col] = fmaxf(acc[r], 0.0f);
    }
  }
}

// ---------------------------------------------------------------------------
extern "C" void kernel_launch(void* const* d_in, const int* in_sizes, int n_in,
                              void* d_out, int out_size, void* d_ws, size_t ws_size,
                              hipStream_t stream) {
  const float* vfeat  = (const float*)d_in[0];
  const float* vcoord = (const float*)d_in[1];
  const float* qcoord = (const float*)d_in[2];
  const int*   kidx   = (const int*)  d_in[3];
  const float* n1g    = (const float*)d_in[4];
  const float* n1b    = (const float*)d_in[5];
  const float* qpw    = (const float*)d_in[6];
  const float* qpb    = (const float*)d_in[7];
  const float* kpw    = (const float*)d_in[8];
  const float* kpb    = (const float*)d_in[9];
  const float* in_w   = (const float*)d_in[10];
  const float* in_b   = (const float*)d_in[11];
  const float* out_w  = (const float*)d_in[12];
  const float* out_b  = (const float*)d_in[13];
  const float* n2g    = (const float*)d_in[14];
  const float* n2b    = (const float*)d_in[15];
  const float* l1w    = (const float*)d_in[16];
  const float* l1b    = (const float*)d_in[17];
  const float* l2w    = (const float*)d_in[18];
  const float* l2b    = (const float*)d_in[19];
  const float* fw     = (const float*)d_in[20];
  const float* fb     = (const float*)d_in[21];
  float* out = (float*)d_out;

  unsigned short* KVh = (unsigned short*)d_ws;          // 8*NVOX*32 shorts (20.5 MB)
  __hip_bfloat16* Gb = (__hip_bfloat16*)(KVh + (size_t)8*NVOX*32);  // NVOX*CH bf16
  __hip_bfloat16* Wb = Gb + (size_t)NVOX*CH;            // 256*CH bf16
  __hip_bfloat16* Eb = Wb + (size_t)2*CH*CH;            // 98304 bf16 epi weights
  float* qb = (float*)(Eb + 98304);                     // NQRY*CH f32
  float* cx = qb + (size_t)NQRY*CH;                     // NQRY*CH f32
  unsigned* sink = (unsigned*)(cx + (size_t)NQRY*CH);   // 1 dword DCE guard

  k_prep   <<<NVOX/16 + 32 + NQRY/16, 256, 0, stream>>>(
      vfeat, vcoord, n1g, n1b, kpw, kpb, in_w, in_b,
      out_w, l1w, l2w, fw, qcoord, qpw, qpb, Gb, Wb, Eb, qb);
  k_kv_gemm<<<(NVOX/64)*4, 256, 0, stream>>>(Gb, Wb, in_b, KVh);
  k_warm   <<<1112, 256, 0, stream>>>((const uint4*)KVh, (const uint4*)kidx,
                                      (const uint4*)qb, sink);
  k_attn   <<<(NQRY/8)*8, 256, 0, stream>>>(KVh, qb, kidx, cx);
  k_epi    <<<NQRY/16, 256, 0, stream>>>(cx, Eb, out_b, n2g, n2b, l1b, l2b, fb, out);
}

// Round 10
// 208.204 us; speedup vs baseline: 1.0613x; 1.0142x over previous
//
#include <hip/hip_runtime.h>
#include <hip/hip_bf16.h>
#include <math.h>

// Problem constants (fixed by reference).
constexpr int NVOX = 40000;
constexpr int NQRY = 8192;
constexpr int KK   = 96;
constexpr int CH   = 128;
constexpr int FFD  = 256;

typedef __attribute__((ext_vector_type(8))) short short8;
typedef __attribute__((ext_vector_type(4))) float float4v;

__device__ inline float bflo(unsigned u) { return __uint_as_float(u << 16); }
__device__ inline float bfhi(unsigned u) { return __uint_as_float(u & 0xffff0000u); }
__device__ inline unsigned short f2bf(float x) {
  union { float f; unsigned u; } a; a.f = x;
  const unsigned r = a.u + 0x7fffu + ((a.u >> 16) & 1u);  // round-to-nearest-even
  return (unsigned short)(r >> 16);
}
__device__ inline unsigned pack2(float lo, float hi) {
  return (unsigned)f2bf(lo) | ((unsigned)f2bf(hi) << 16);
}

// ---------------------------------------------------------------------------
// Kernel 1: prep (merged) —
//  blocks [0, NVOX/16):         per-voxel LN + relu(key-pos) -> Gb bf16
//  blocks [NVOX/16, +8):        Wkv -> Wb bf16
//  blocks [NVOX/16+8, +24):     epilogue weights -> Eb bf16
//  blocks [NVOX/16+32, +512):   q = relu(qc@q_pos_w.T+b) @ wq.T + bq -> qb f32
// ---------------------------------------------------------------------------
__global__ __launch_bounds__(256) void k_prep(
    const float* __restrict__ vfeat, const float* __restrict__ vcoord,
    const float* __restrict__ n1g, const float* __restrict__ n1b,
    const float* __restrict__ kpw, const float* __restrict__ kpb,
    const float* __restrict__ in_w, const float* __restrict__ in_b,
    const float* __restrict__ ow, const float* __restrict__ l1w,
    const float* __restrict__ l2w, const float* __restrict__ fw,
    const float* __restrict__ qcoord,
    const float* __restrict__ qpw, const float* __restrict__ qpb,
    __hip_bfloat16* __restrict__ Gb, __hip_bfloat16* __restrict__ Wb,
    __hip_bfloat16* __restrict__ Eb, float* __restrict__ qout) {
  const int b = blockIdx.x;
  const int t = threadIdx.x;
  if (b < NVOX/16) {
    const int vloc = t >> 4;
    const int l    = t & 15;
    const int j = b * 16 + vloc;
    const float4* vrow = reinterpret_cast<const float4*>(vfeat + (size_t)j * CH);
    const float4 x0 = vrow[l*2], x1 = vrow[l*2+1];
    float s  = x0.x+x0.y+x0.z+x0.w + x1.x+x1.y+x1.z+x1.w;
    float ss = x0.x*x0.x+x0.y*x0.y+x0.z*x0.z+x0.w*x0.w
             + x1.x*x1.x+x1.y*x1.y+x1.z*x1.z+x1.w*x1.w;
    #pragma unroll
    for (int m = 8; m >= 1; m >>= 1) { s += __shfl_xor(s, m); ss += __shfl_xor(ss, m); }
    const float mean = s * (1.0f/CH);
    const float var  = ss * (1.0f/CH) - mean*mean;
    const float rstd = 1.0f / sqrtf(var + 1e-5f);
    const float c0 = vcoord[j*3+0], c1 = vcoord[j*3+1], c2 = vcoord[j*3+2];
    const float xv[8] = {x0.x,x0.y,x0.z,x0.w,x1.x,x1.y,x1.z,x1.w};
    float gv[8];
    #pragma unroll
    for (int u = 0; u < 8; u++) {
      const int c = l*8 + u;
      const float vf = (xv[u] - mean) * rstd * n1g[c] + n1b[c];
      const float kp = fmaf(c0, kpw[c*3+0], fmaf(c1, kpw[c*3+1], fmaf(c2, kpw[c*3+2], kpb[c])));
      gv[u] = vf + fmaxf(kp, 0.0f);
    }
    const uint4 pk = make_uint4(pack2(gv[0],gv[1]), pack2(gv[2],gv[3]),
                                pack2(gv[4],gv[5]), pack2(gv[6],gv[7]));
    *reinterpret_cast<uint4*>(Gb + (size_t)j*CH + l*8) = pk;
  } else if (b < NVOX/16 + 32) {
    const int idx = b - NVOX/16;
    const float* src;
    __hip_bfloat16* dst;
    if (idx < 8) {
      const int e = (idx * 256 + t) * 16;
      src = in_w + (size_t)CH*CH + e;
      dst = Wb + e;
    } else {
      const int f = ((idx - 8) * 256 + t) * 16;   // 0..98303
      dst = Eb + f;
      if      (f < 16384) src = ow  + f;
      else if (f < 49152) src = l1w + (f - 16384);
      else if (f < 81920) src = l2w + (f - 49152);
      else                src = fw  + (f - 81920);
    }
    float v[16];
    #pragma unroll
    for (int u = 0; u < 4; u++) {
      const float4 fq = *reinterpret_cast<const float4*>(src + u*4);
      v[u*4+0]=fq.x; v[u*4+1]=fq.y; v[u*4+2]=fq.z; v[u*4+3]=fq.w;
    }
    uint4* o = reinterpret_cast<uint4*>(dst);
    o[0] = make_uint4(pack2(v[0],v[1]), pack2(v[2],v[3]),
                      pack2(v[4],v[5]), pack2(v[6],v[7]));
    o[1] = make_uint4(pack2(v[8],v[9]), pack2(v[10],v[11]),
                      pack2(v[12],v[13]), pack2(v[14],v[15]));
  } else {
    // q projection: 16 queries per block.
    __shared__ float qf[16][CH];
    const int qbase = (b - (NVOX/16 + 32)) * 16;
    #pragma unroll
    for (int i = 0; i < 8; i++) {
      const int e = t + 256*i;
      const int qv = e >> 7, c = e & 127;
      const int qq = qbase + qv;
      const float v = fmaf(qcoord[qq*3+0], qpw[c*3+0],
                      fmaf(qcoord[qq*3+1], qpw[c*3+1],
                      fmaf(qcoord[qq*3+2], qpw[c*3+2], qpb[c])));
      qf[qv][c] = fmaxf(v, 0.0f);
    }
    __syncthreads();
    const int oc = t & 127, half = t >> 7;
    const float* wrow = in_w + (size_t)oc * CH;
    const float bia = in_b[oc];
    float acc[8];
    #pragma unroll
    for (int v = 0; v < 8; v++) acc[v] = bia;
    for (int c = 0; c < CH; c += 4) {
      const float4 w4 = *reinterpret_cast<const float4*>(wrow + c);
      #pragma unroll
      for (int v = 0; v < 8; v++) {
        const float4 g4 = *reinterpret_cast<const float4*>(&qf[half*8+v][c]);
        acc[v] = fmaf(g4.x, w4.x, fmaf(g4.y, w4.y, fmaf(g4.z, w4.z, fmaf(g4.w, w4.w, acc[v]))));
      }
    }
    #pragma unroll
    for (int v = 0; v < 8; v++) qout[(size_t)(qbase + half*8 + v)*CH + oc] = acc[v];
  }
}

// ---------------------------------------------------------------------------
// Kernel 1b: KV projection GEMM via MFMA bf16 — HEAD-PINNED grid.
// blockIdx&7 = head (same %8 XCD mapping as k_attn) so the head's KV lines
// land dirty in the SAME XCD L2 that k_attn will read them from.
// Block: 64 voxels x (16 K-ch + 16 V-ch) of one head; wave w -> voxels w*16..+15.
// KVh[head][voxel][32]: shorts 0..15 = K-slice, 16..31 = V-slice (one line).
// ---------------------------------------------------------------------------
__global__ __launch_bounds__(256) void k_kv_gemm(
    const __hip_bfloat16* __restrict__ Gb, const __hip_bfloat16* __restrict__ Wb,
    const float* __restrict__ in_b,
    unsigned short* __restrict__ KVh) {
  __shared__ unsigned short ldsD[64][40];   // 32 data + 8 pad
  const int t = threadIdx.x;
  const int w = t >> 6;
  const int lane = t & 63;
  const int col = lane & 15;
  const int quad = lane >> 4;
  const int bx = blockIdx.x;
  const int h  = bx & 7;
  const int v0 = (bx >> 3) * 64;
  const int vw = v0 + w*16;

  // A frags: m=col -> voxel vw+col, k = quad*8 + kq*32 (+j inside short8).
  const unsigned short* gRow =
      reinterpret_cast<const unsigned short*>(Gb) + (size_t)(vw + col)*CH + quad*8;
  short8 afrag[4];
  #pragma unroll
  for (int kq = 0; kq < 4; kq++)
    afrag[kq] = *reinterpret_cast<const short8*>(gRow + kq*32);

  const float biaK = in_b[CH   + h*16 + col];
  const float biaV = in_b[2*CH + h*16 + col];
  float4v accK = (float4v){biaK, biaK, biaK, biaK};
  float4v accV = (float4v){biaV, biaV, biaV, biaV};
  const unsigned short* wB = reinterpret_cast<const unsigned short*>(Wb);
  #pragma unroll
  for (int kq = 0; kq < 4; kq++) {
    const short8 bK = *reinterpret_cast<const short8*>(
        wB + (size_t)(h*16 + col)*CH + kq*32 + quad*8);
    accK = __builtin_amdgcn_mfma_f32_16x16x32_bf16(afrag[kq], bK, accK, 0, 0, 0);
    const short8 bV = *reinterpret_cast<const short8*>(
        wB + (size_t)(CH + h*16 + col)*CH + kq*32 + quad*8);
    accV = __builtin_amdgcn_mfma_f32_16x16x32_bf16(afrag[kq], bV, accV, 0, 0, 0);
  }
  #pragma unroll
  for (int r = 0; r < 4; r++) {
    const int row = w*16 + quad*4 + r;
    ldsD[row][col]      = f2bf(accK[r]);
    ldsD[row][16 + col] = f2bf(accV[r]);
  }
  __syncthreads();
  // Coalesced writeout: thread -> (voxel = t>>2, 16-B quarter of the 64-B line).
  const int v  = t >> 2;
  const int qq = t & 3;
  const uint4 d = *reinterpret_cast<const uint4*>(&ldsD[v][qq*8]);
  *reinterpret_cast<uint4*>(KVh + ((size_t)h*NVOX + v0 + v)*32 + qq*8) = d;
}

// ---------------------------------------------------------------------------
// Kernel 2b: k_warm — head-pinned L2 sweep (KV only). Blocks b&7 = head;
// mostly L2-hits now that kv_gemm writes are pinned; guarantees residency
// against eviction by the Gb/weight streams. XOR-consume prevents DCE.
// ---------------------------------------------------------------------------
__global__ __launch_bounds__(256) void k_warm(
    const uint4* __restrict__ kv4, unsigned* __restrict__ sink) {
  const int b = blockIdx.x;
  const int t = threadIdx.x;
  const int h = b & 7, chunk = b >> 3;            // chunk 0..124
  const uint4* p = kv4 + (size_t)h*160000 + (size_t)chunk*1280 + t;
  unsigned acc = 0;
  #pragma unroll
  for (int i = 0; i < 5; i++) {
    const uint4 v = p[i*256];
    acc ^= v.x ^ v.y ^ v.z ^ v.w;
  }
  if (acc == 0xDEADBEEFu) sink[0] = acc;          // never taken in practice
}

// ---------------------------------------------------------------------------
// Kernel 3: attention (round-6 structure). Block = (8q, 1h);
// blockIdx.x = qg*8 + h so round-robin XCD dispatch pins head<->XCD.
// 4 lanes per (q,k): each loads dwordx4 -> full 64-B line in ONE request.
// r0/r1 = K halves (score via shfl_xor(.,1)); r2/r3 = V halves, kept in
// registers across softmax, accumulated into ctx locally, reduced via LDS.
// ---------------------------------------------------------------------------
__global__ __launch_bounds__(256) void k_attn(
    const unsigned short* __restrict__ KVh,
    const float* __restrict__ qg, const int* __restrict__ kidx,
    float* __restrict__ ctxg) {
  __shared__ float qs[8][16];
  __shared__ float sc[8*104];     // stride 104: conflict-free softmax/ctx reads
  __shared__ float red[128][9];   // slot-padded ctx partials
  __shared__ float rden[8];
  const int t    = threadIdx.x;
  const int h    = blockIdx.x & 7;
  const int n0   = (blockIdx.x >> 3) * 8;
  const int w    = t >> 6;
  const int lane = t & 63;
  const int quad = lane >> 2;     // 0..15
  const int r    = lane & 3;      // lane role within quad
  const int qh   = quad >> 3;     // 0/1: which of the wave's 2 queries
  const int g    = quad & 7;      // key slot group: keys g, g+8, ..., g+88
  const int q_l  = 2*w + qh;      // block-local query 0..7
  const unsigned short* KVbase = KVh + (size_t)h * NVOX * 32;

  if (t < 128) {
    const int q = t >> 4, d = t & 15;
    qs[q][d] = qg[(size_t)(n0 + q)*CH + h*16 + d];
  }
  // Loads: 12 keys per quad; each lane fetches its 16-B quarter of the line.
  unsigned msk = 0;
  uint4 kvbuf[12];
  const int krow = (n0 + q_l)*KK + g;
  #pragma unroll
  for (int it = 0; it < 12; it++) {
    const int j0 = kidx[krow + it*8];
    msk |= (unsigned)(j0 < 0) << it;
    const int j = (j0 < 0) ? 0 : j0;   // clamp like reference
    kvbuf[it] = *reinterpret_cast<const uint4*>(KVbase + (size_t)j*32 + r*8);
  }
  __syncthreads();
  // Scores: r0/r1 lanes hold K halves; q half selected by r&1.
  const float4 qa = *reinterpret_cast<const float4*>(&qs[q_l][(r & 1)*8]);
  const float4 qb = *reinterpret_cast<const float4*>(&qs[q_l][(r & 1)*8 + 4]);
  #pragma unroll
  for (int it = 0; it < 12; it++) {
    const uint4 kv = kvbuf[it];
    float s = 0.0f;
    s = fmaf(qa.x, bflo(kv.x), s); s = fmaf(qa.y, bfhi(kv.x), s);
    s = fmaf(qa.z, bflo(kv.y), s); s = fmaf(qa.w, bfhi(kv.y), s);
    s = fmaf(qb.x, bflo(kv.z), s); s = fmaf(qb.y, bfhi(kv.z), s);
    s = fmaf(qb.z, bflo(kv.w), s); s = fmaf(qb.w, bfhi(kv.w), s);
    s += __shfl_xor(s, 1);          // r0+r1 (K full dot); r2+r3 garbage unused
    if (r == 0)
      sc[q_l*104 + g + it*8] = ((msk >> it) & 1) ? -1e9f : s * 0.25f;
  }
  __syncthreads();
  // Softmax per query: 16 lanes over 96 keys.
  if (t < 128) {
    const int q = t >> 4, l = t & 15;
    float mx = -3e38f;
    #pragma unroll
    for (int k = l; k < KK; k += 16) mx = fmaxf(mx, sc[q*104 + k]);
    #pragma unroll
    for (int m = 8; m >= 1; m >>= 1) mx = fmaxf(mx, __shfl_xor(mx, m));
    float sum = 0.0f;
    #pragma unroll
    for (int k = l; k < KK; k += 16) {
      const float p = __expf(sc[q*104 + k] - mx);   // masked -> exactly 0
      sc[q*104 + k] = p;
      sum += p;
    }
    #pragma unroll
    for (int m = 8; m >= 1; m >>= 1) sum += __shfl_xor(sum, m);
    if (l == 0) rden[q] = 1.0f / sum;
  }
  __syncthreads();
  // ctx: r2/r3 lanes accumulate their V half over their 12 keys.
  {
    float acc[8] = {0,0,0,0,0,0,0,0};
    #pragma unroll
    for (int it = 0; it < 12; it++) {
      const float wg = sc[q_l*104 + g + it*8];   // broadcast within quad
      const uint4 kv = kvbuf[it];
      acc[0] = fmaf(wg, bflo(kv.x), acc[0]); acc[1] = fmaf(wg, bfhi(kv.x), acc[1]);
      acc[2] = fmaf(wg, bflo(kv.y), acc[2]); acc[3] = fmaf(wg, bfhi(kv.y), acc[3]);
      acc[4] = fmaf(wg, bflo(kv.z), acc[4]); acc[5] = fmaf(wg, bfhi(kv.z), acc[5]);
      acc[6] = fmaf(wg, bflo(kv.w), acc[6]); acc[7] = fmaf(wg, bfhi(kv.w), acc[7]);
    }
    if (r >= 2) {
      const int slot = q_l*16 + g*2 + (r - 2);   // 0..127
      #pragma unroll
      for (int u = 0; u < 8; u++) red[slot][u] = acc[u];
    }
  }
  __syncthreads();
  // Reduce 8 slot-groups per (query, channel) and store.
  if (t < 128) {
    const int q = t >> 4, d = t & 15;
    const int half = d >> 3, u = d & 7;
    float s = 0.0f;
    #pragma unroll
    for (int gg = 0; gg < 8; gg++) s += red[q*16 + gg*2 + half][u];
    ctxg[(size_t)(n0 + q)*CH + h*16 + d] = s * rden[q];
  }
}

// ---------------------------------------------------------------------------
// Kernel 4: epilogue via MFMA bf16 (unchanged).
// ---------------------------------------------------------------------------
__global__ __launch_bounds__(256) void k_epi(
    const float* __restrict__ ctxg, const __hip_bfloat16* __restrict__ Eb,
    const float* __restrict__ ob,
    const float* __restrict__ n2g, const float* __restrict__ n2b,
    const float* __restrict__ l1b, const float* __restrict__ l2b,
    const float* __restrict__ fb,
    float* __restrict__ outp) {
  __shared__ unsigned short csb[16][136];
  __shared__ float attnS[16][132];
  __shared__ unsigned short hb[16][136];
  __shared__ unsigned short a1b[16][264];
  __shared__ unsigned short xb[16][136];
  const unsigned short* owb  = reinterpret_cast<const unsigned short*>(Eb);
  const unsigned short* l1wb = owb + 16384;
  const unsigned short* l2wb = owb + 49152;
  const unsigned short* fwb  = owb + 81920;

  const int t = threadIdx.x;
  const int w = t >> 6;
  const int lane = t & 63;
  const int col = lane & 15;
  const int quad = lane >> 4;
  const int qbase = blockIdx.x * 16;

  {
    const int e = t * 8;
    const int row = e >> 7, cc = e & 127;
    const float4* src = reinterpret_cast<const float4*>(ctxg + (size_t)(qbase+row)*CH + cc);
    const float4 x0 = src[0], x1 = src[1];
    *reinterpret_cast<uint4*>(&csb[row][cc]) =
        make_uint4(pack2(x0.x,x0.y), pack2(x0.z,x0.w), pack2(x1.x,x1.y), pack2(x1.z,x1.w));
  }
  __syncthreads();
  {
    short8 af[4];
    #pragma unroll
    for (int kq = 0; kq < 4; kq++)
      af[kq] = *reinterpret_cast<const short8*>(&csb[col][quad*8 + kq*32]);
    #pragma unroll
    for (int j = 0; j < 2; j++) {
      const int n0 = w*32 + j*16;
      const float bia = ob[n0 + col];
      float4v acc = (float4v){bia, bia, bia, bia};
      #pragma unroll
      for (int kq = 0; kq < 4; kq++) {
        const short8 bf = *reinterpret_cast<const short8*>(
            owb + (size_t)(n0 + col)*CH + kq*32 + quad*8);
        acc = __builtin_amdgcn_mfma_f32_16x16x32_bf16(af[kq], bf, acc, 0, 0, 0);
      }
      #pragma unroll
      for (int r = 0; r < 4; r++) attnS[quad*4 + r][n0 + col] = acc[r];
    }
  }
  __syncthreads();
  {
    const int row = t >> 4, l = t & 15;
    float s = 0.0f, ss = 0.0f;
    #pragma unroll
    for (int c = l; c < CH; c += 16) { const float x = attnS[row][c]; s += x; ss += x*x; }
    #pragma unroll
    for (int m = 8; m >= 1; m >>= 1) { s += __shfl_xor(s, m); ss += __shfl_xor(ss, m); }
    const float mean = s * (1.0f/CH);
    const float var  = ss * (1.0f/CH) - mean*mean;
    const float rstd = 1.0f / sqrtf(var + 1e-5f);
    #pragma unroll
    for (int c = l; c < CH; c += 16)
      hb[row][c] = f2bf((attnS[row][c] - mean) * rstd * n2g[c] + n2b[c]);
  }
  __syncthreads();
  {
    short8 af[4];
    #pragma unroll
    for (int kq = 0; kq < 4; kq++)
      af[kq] = *reinterpret_cast<const short8*>(&hb[col][quad*8 + kq*32]);
    #pragma unroll
    for (int j = 0; j < 4; j++) {
      const int n0 = w*64 + j*16;
      const float bia = l1b[n0 + col];
      float4v acc = (float4v){bia, bia, bia, bia};
      #pragma unroll
      for (int kq = 0; kq < 4; kq++) {
        const short8 bf = *reinterpret_cast<const short8*>(
            l1wb + (size_t)(n0 + col)*CH + kq*32 + quad*8);
        acc = __builtin_amdgcn_mfma_f32_16x16x32_bf16(af[kq], bf, acc, 0, 0, 0);
      }
      #pragma unroll
      for (int r = 0; r < 4; r++)
        a1b[quad*4 + r][n0 + col] = f2bf(fmaxf(acc[r], 0.0f));
    }
  }
  __syncthreads();
  {
    short8 af[8];
    #pragma unroll
    for (int kq = 0; kq < 8; kq++)
      af[kq] = *reinterpret_cast<const short8*>(&a1b[col][quad*8 + kq*32]);
    #pragma unroll
    for (int j = 0; j < 2; j++) {
      const int n0 = w*32 + j*16;
      const float bia = l2b[n0 + col];
      float4v acc = (float4v){bia, bia, bia, bia};
      #pragma unroll
      for (int kq = 0; kq < 8; kq++) {
        const short8 bf = *reinterpret_cast<const short8*>(
            l2wb + (size_t)(n0 + col)*FFD + kq*32 + quad*8);
        acc = __builtin_amdgcn_mfma_f32_16x16x32_bf16(af[kq], bf, acc, 0, 0, 0);
      }
      #pragma unroll
      for (int r = 0; r < 4; r++)
        xb[quad*4 + r][n0 + col] = f2bf(acc[r] + attnS[quad*4 + r][n0 + col]);
    }
  }
  __syncthreads();
  {
    short8 af[4];
    #pragma unroll
    for (int kq = 0; kq < 4; kq++)
      af[kq] = *reinterpret_cast<const short8*>(&xb[col][quad*8 + kq*32]);
    #pragma unroll
    for (int j = 0; j < 2; j++) {
      const int n0 = w*32 + j*16;
      const float bia = fb[n0 + col];
      float4v acc = (float4v){bia, bia, bia, bia};
      #pragma unroll
      for (int kq = 0; kq < 4; kq++) {
        const short8 bf = *reinterpret_cast<const short8*>(
            fwb + (size_t)(n0 + col)*CH + kq*32 + quad*8);
        acc = __builtin_amdgcn_mfma_f32_16x16x32_bf16(af[kq], bf, acc, 0, 0, 0);
      }
      #pragma unroll
      for (int r = 0; r < 4; r++)
        outp[(size_t)(qbase + quad*4 + r)*CH + n0 + col] = fmaxf(acc[r], 0.0f);
    }
  }
}

// ---------------------------------------------------------------------------
extern "C" void kernel_launch(void* const* d_in, const int* in_sizes, int n_in,
                              void* d_out, int out_size, void* d_ws, size_t ws_size,
                              hipStream_t stream) {
  const float* vfeat  = (const float*)d_in[0];
  const float* vcoord = (const float*)d_in[1];
  const float* qcoord = (const float*)d_in[2];
  const int*   kidx   = (const int*)  d_in[3];
  const float* n1g    = (const float*)d_in[4];
  const float* n1b    = (const float*)d_in[5];
  const float* qpw    = (const float*)d_in[6];
  const float* qpb    = (const float*)d_in[7];
  const float* kpw    = (const float*)d_in[8];
  const float* kpb    = (const float*)d_in[9];
  const float* in_w   = (const float*)d_in[10];
  const float* in_b   = (const float*)d_in[11];
  const float* out_w  = (const float*)d_in[12];
  const float* out_b  = (const float*)d_in[13];
  const float* n2g    = (const float*)d_in[14];
  const float* n2b    = (const float*)d_in[15];
  const float* l1w    = (const float*)d_in[16];
  const float* l1b    = (const float*)d_in[17];
  const float* l2w    = (const float*)d_in[18];
  const float* l2b    = (const float*)d_in[19];
  const float* fw     = (const float*)d_in[20];
  const float* fb     = (const float*)d_in[21];
  float* out = (float*)d_out;

  unsigned short* KVh = (unsigned short*)d_ws;          // 8*NVOX*32 shorts (20.5 MB)
  __hip_bfloat16* Gb = (__hip_bfloat16*)(KVh + (size_t)8*NVOX*32);  // NVOX*CH bf16
  __hip_bfloat16* Wb = Gb + (size_t)NVOX*CH;            // 256*CH bf16
  __hip_bfloat16* Eb = Wb + (size_t)2*CH*CH;            // 98304 bf16 epi weights
  float* qb = (float*)(Eb + 98304);                     // NQRY*CH f32
  float* cx = qb + (size_t)NQRY*CH;                     // NQRY*CH f32
  unsigned* sink = (unsigned*)(cx + (size_t)NQRY*CH);   // 1 dword DCE guard

  k_prep   <<<NVOX/16 + 32 + NQRY/16, 256, 0, stream>>>(
      vfeat, vcoord, n1g, n1b, kpw, kpb, in_w, in_b,
      out_w, l1w, l2w, fw, qcoord, qpw, qpb, Gb, Wb, Eb, qb);
  k_kv_gemm<<<(NVOX/64)*8, 256, 0, stream>>>(Gb, Wb, in_b, KVh);
  k_warm   <<<1000, 256, 0, stream>>>((const uint4*)KVh, sink);
  k_attn   <<<(NQRY/8)*8, 256, 0, stream>>>(KVh, qb, kidx, cx);
  k_epi    <<<NQRY/16, 256, 0, stream>>>(cx, Eb, out_b, n2g, n2b, l1b, l2b, fb, out);
}

// Round 11
// 201.776 us; speedup vs baseline: 1.0951x; 1.0319x over previous
//
#include <hip/hip_runtime.h>
#include <hip/hip_bf16.h>
#include <math.h>

// Problem constants (fixed by reference).
constexpr int NVOX = 40000;
constexpr int NQRY = 8192;
constexpr int KK   = 96;
constexpr int CH   = 128;
constexpr int FFD  = 256;

typedef __attribute__((ext_vector_type(8))) short short8;
typedef __attribute__((ext_vector_type(4))) float float4v;

__device__ inline float bflo(unsigned u) { return __uint_as_float(u << 16); }
__device__ inline float bfhi(unsigned u) { return __uint_as_float(u & 0xffff0000u); }
__device__ inline unsigned short f2bf(float x) {
  union { float f; unsigned u; } a; a.f = x;
  const unsigned r = a.u + 0x7fffu + ((a.u >> 16) & 1u);  // round-to-nearest-even
  return (unsigned short)(r >> 16);
}
__device__ inline unsigned pack2(float lo, float hi) {
  return (unsigned)f2bf(lo) | ((unsigned)f2bf(hi) << 16);
}

// ---------------------------------------------------------------------------
// Kernel 1: prep (merged) —
//  blocks [0, NVOX/16):         per-voxel LN + relu(key-pos) -> Gb bf16
//  blocks [NVOX/16, +8):        Wkv -> Wb bf16
//  blocks [NVOX/16+8, +24):     epilogue weights -> Eb bf16
//  blocks [NVOX/16+32, +512):   q = relu(qc@q_pos_w.T+b) @ wq.T + bq -> qb f32
// ---------------------------------------------------------------------------
__global__ __launch_bounds__(256) void k_prep(
    const float* __restrict__ vfeat, const float* __restrict__ vcoord,
    const float* __restrict__ n1g, const float* __restrict__ n1b,
    const float* __restrict__ kpw, const float* __restrict__ kpb,
    const float* __restrict__ in_w, const float* __restrict__ in_b,
    const float* __restrict__ ow, const float* __restrict__ l1w,
    const float* __restrict__ l2w, const float* __restrict__ fw,
    const float* __restrict__ qcoord,
    const float* __restrict__ qpw, const float* __restrict__ qpb,
    __hip_bfloat16* __restrict__ Gb, __hip_bfloat16* __restrict__ Wb,
    __hip_bfloat16* __restrict__ Eb, float* __restrict__ qout) {
  const int b = blockIdx.x;
  const int t = threadIdx.x;
  if (b < NVOX/16) {
    const int vloc = t >> 4;
    const int l    = t & 15;
    const int j = b * 16 + vloc;
    const float4* vrow = reinterpret_cast<const float4*>(vfeat + (size_t)j * CH);
    const float4 x0 = vrow[l*2], x1 = vrow[l*2+1];
    float s  = x0.x+x0.y+x0.z+x0.w + x1.x+x1.y+x1.z+x1.w;
    float ss = x0.x*x0.x+x0.y*x0.y+x0.z*x0.z+x0.w*x0.w
             + x1.x*x1.x+x1.y*x1.y+x1.z*x1.z+x1.w*x1.w;
    #pragma unroll
    for (int m = 8; m >= 1; m >>= 1) { s += __shfl_xor(s, m); ss += __shfl_xor(ss, m); }
    const float mean = s * (1.0f/CH);
    const float var  = ss * (1.0f/CH) - mean*mean;
    const float rstd = 1.0f / sqrtf(var + 1e-5f);
    const float c0 = vcoord[j*3+0], c1 = vcoord[j*3+1], c2 = vcoord[j*3+2];
    const float xv[8] = {x0.x,x0.y,x0.z,x0.w,x1.x,x1.y,x1.z,x1.w};
    float gv[8];
    #pragma unroll
    for (int u = 0; u < 8; u++) {
      const int c = l*8 + u;
      const float vf = (xv[u] - mean) * rstd * n1g[c] + n1b[c];
      const float kp = fmaf(c0, kpw[c*3+0], fmaf(c1, kpw[c*3+1], fmaf(c2, kpw[c*3+2], kpb[c])));
      gv[u] = vf + fmaxf(kp, 0.0f);
    }
    const uint4 pk = make_uint4(pack2(gv[0],gv[1]), pack2(gv[2],gv[3]),
                                pack2(gv[4],gv[5]), pack2(gv[6],gv[7]));
    *reinterpret_cast<uint4*>(Gb + (size_t)j*CH + l*8) = pk;
  } else if (b < NVOX/16 + 32) {
    const int idx = b - NVOX/16;
    const float* src;
    __hip_bfloat16* dst;
    if (idx < 8) {
      const int e = (idx * 256 + t) * 16;
      src = in_w + (size_t)CH*CH + e;
      dst = Wb + e;
    } else {
      const int f = ((idx - 8) * 256 + t) * 16;   // 0..98303
      dst = Eb + f;
      if      (f < 16384) src = ow  + f;
      else if (f < 49152) src = l1w + (f - 16384);
      else if (f < 81920) src = l2w + (f - 49152);
      else                src = fw  + (f - 81920);
    }
    float v[16];
    #pragma unroll
    for (int u = 0; u < 4; u++) {
      const float4 fq = *reinterpret_cast<const float4*>(src + u*4);
      v[u*4+0]=fq.x; v[u*4+1]=fq.y; v[u*4+2]=fq.z; v[u*4+3]=fq.w;
    }
    uint4* o = reinterpret_cast<uint4*>(dst);
    o[0] = make_uint4(pack2(v[0],v[1]), pack2(v[2],v[3]),
                      pack2(v[4],v[5]), pack2(v[6],v[7]));
    o[1] = make_uint4(pack2(v[8],v[9]), pack2(v[10],v[11]),
                      pack2(v[12],v[13]), pack2(v[14],v[15]));
  } else {
    // q projection: 16 queries per block.
    __shared__ float qf[16][CH];
    const int qbase = (b - (NVOX/16 + 32)) * 16;
    #pragma unroll
    for (int i = 0; i < 8; i++) {
      const int e = t + 256*i;
      const int qv = e >> 7, c = e & 127;
      const int qq = qbase + qv;
      const float v = fmaf(qcoord[qq*3+0], qpw[c*3+0],
                      fmaf(qcoord[qq*3+1], qpw[c*3+1],
                      fmaf(qcoord[qq*3+2], qpw[c*3+2], qpb[c])));
      qf[qv][c] = fmaxf(v, 0.0f);
    }
    __syncthreads();
    const int oc = t & 127, half = t >> 7;
    const float* wrow = in_w + (size_t)oc * CH;
    const float bia = in_b[oc];
    float acc[8];
    #pragma unroll
    for (int v = 0; v < 8; v++) acc[v] = bia;
    for (int c = 0; c < CH; c += 4) {
      const float4 w4 = *reinterpret_cast<const float4*>(wrow + c);
      #pragma unroll
      for (int v = 0; v < 8; v++) {
        const float4 g4 = *reinterpret_cast<const float4*>(&qf[half*8+v][c]);
        acc[v] = fmaf(g4.x, w4.x, fmaf(g4.y, w4.y, fmaf(g4.z, w4.z, fmaf(g4.w, w4.w, acc[v]))));
      }
    }
    #pragma unroll
    for (int v = 0; v < 8; v++) qout[(size_t)(qbase + half*8 + v)*CH + oc] = acc[v];
  }
}

// ---------------------------------------------------------------------------
// Kernel 1b: KV projection GEMM via MFMA bf16 — HEAD-PINNED grid.
// blockIdx&7 = head (same %8 XCD mapping as k_attn) so the head's KV lines
// land dirty in the SAME XCD L2 that k_attn will read them from.
// ---------------------------------------------------------------------------
__global__ __launch_bounds__(256) void k_kv_gemm(
    const __hip_bfloat16* __restrict__ Gb, const __hip_bfloat16* __restrict__ Wb,
    const float* __restrict__ in_b,
    unsigned short* __restrict__ KVh) {
  __shared__ unsigned short ldsD[64][40];   // 32 data + 8 pad
  const int t = threadIdx.x;
  const int w = t >> 6;
  const int lane = t & 63;
  const int col = lane & 15;
  const int quad = lane >> 4;
  const int bx = blockIdx.x;
  const int h  = bx & 7;
  const int v0 = (bx >> 3) * 64;
  const int vw = v0 + w*16;

  const unsigned short* gRow =
      reinterpret_cast<const unsigned short*>(Gb) + (size_t)(vw + col)*CH + quad*8;
  short8 afrag[4];
  #pragma unroll
  for (int kq = 0; kq < 4; kq++)
    afrag[kq] = *reinterpret_cast<const short8*>(gRow + kq*32);

  const float biaK = in_b[CH   + h*16 + col];
  const float biaV = in_b[2*CH + h*16 + col];
  float4v accK = (float4v){biaK, biaK, biaK, biaK};
  float4v accV = (float4v){biaV, biaV, biaV, biaV};
  const unsigned short* wB = reinterpret_cast<const unsigned short*>(Wb);
  #pragma unroll
  for (int kq = 0; kq < 4; kq++) {
    const short8 bK = *reinterpret_cast<const short8*>(
        wB + (size_t)(h*16 + col)*CH + kq*32 + quad*8);
    accK = __builtin_amdgcn_mfma_f32_16x16x32_bf16(afrag[kq], bK, accK, 0, 0, 0);
    const short8 bV = *reinterpret_cast<const short8*>(
        wB + (size_t)(CH + h*16 + col)*CH + kq*32 + quad*8);
    accV = __builtin_amdgcn_mfma_f32_16x16x32_bf16(afrag[kq], bV, accV, 0, 0, 0);
  }
  #pragma unroll
  for (int r = 0; r < 4; r++) {
    const int row = w*16 + quad*4 + r;
    ldsD[row][col]      = f2bf(accK[r]);
    ldsD[row][16 + col] = f2bf(accV[r]);
  }
  __syncthreads();
  const int v  = t >> 2;
  const int qq = t & 3;
  const uint4 d = *reinterpret_cast<const uint4*>(&ldsD[v][qq*8]);
  *reinterpret_cast<uint4*>(KVh + ((size_t)h*NVOX + v0 + v)*32 + qq*8) = d;
}

// ---------------------------------------------------------------------------
// Kernel 3: attention with FUSED L2 warm prologue. Block = (8q, 1h);
// blockIdx.x = qg*8 + h (head<->XCD pinning). Prologue: lanes t<40 stream 40
// sequential KV lines of this head (1024 blocks/head cover ~all 40000 lines),
// issued at kernel start, consumed only at the very end (XOR sink) -> the
// warm fully overlaps the gather/softmax work. Replaces the k_warm dispatch.
// ---------------------------------------------------------------------------
__global__ __launch_bounds__(256) void k_attn(
    const unsigned short* __restrict__ KVh,
    const float* __restrict__ qg, const int* __restrict__ kidx,
    float* __restrict__ ctxg, unsigned* __restrict__ sink) {
  __shared__ float qs[8][16];
  __shared__ float sc[8*104];     // stride 104: conflict-free softmax/ctx reads
  __shared__ float red[128][9];   // slot-padded ctx partials
  __shared__ float rden[8];
  const int t    = threadIdx.x;
  const int h    = blockIdx.x & 7;
  const int n0   = (blockIdx.x >> 3) * 8;
  const int w    = t >> 6;
  const int lane = t & 63;
  const int quad = lane >> 2;     // 0..15
  const int r    = lane & 3;      // lane role within quad
  const int qh   = quad >> 3;     // 0/1: which of the wave's 2 queries
  const int g    = quad & 7;      // key slot group: keys g, g+8, ..., g+88
  const int q_l  = 2*w + qh;      // block-local query 0..7
  const unsigned short* KVbase = KVh + (size_t)h * NVOX * 32;

  // Fused warm: stream 40 sequential lines of this head's slice (overlapped).
  uint4 wv = make_uint4(0u, 0u, 0u, 0u);
  if (t < 40) {
    int line = (blockIdx.x >> 3) * 39 + t;
    if (line > NVOX - 1) line = NVOX - 1;
    wv = *reinterpret_cast<const uint4*>(KVbase + (size_t)line * 32);
  }

  if (t < 128) {
    const int q = t >> 4, d = t & 15;
    qs[q][d] = qg[(size_t)(n0 + q)*CH + h*16 + d];
  }
  // Loads: 12 keys per quad; each lane fetches its 16-B quarter of the line.
  unsigned msk = 0;
  uint4 kvbuf[12];
  const int krow = (n0 + q_l)*KK + g;
  #pragma unroll
  for (int it = 0; it < 12; it++) {
    const int j0 = kidx[krow + it*8];
    msk |= (unsigned)(j0 < 0) << it;
    const int j = (j0 < 0) ? 0 : j0;   // clamp like reference
    kvbuf[it] = *reinterpret_cast<const uint4*>(KVbase + (size_t)j*32 + r*8);
  }
  __syncthreads();
  // Scores: r0/r1 lanes hold K halves; q half selected by r&1.
  const float4 qa = *reinterpret_cast<const float4*>(&qs[q_l][(r & 1)*8]);
  const float4 qb = *reinterpret_cast<const float4*>(&qs[q_l][(r & 1)*8 + 4]);
  #pragma unroll
  for (int it = 0; it < 12; it++) {
    const uint4 kv = kvbuf[it];
    float s = 0.0f;
    s = fmaf(qa.x, bflo(kv.x), s); s = fmaf(qa.y, bfhi(kv.x), s);
    s = fmaf(qa.z, bflo(kv.y), s); s = fmaf(qa.w, bfhi(kv.y), s);
    s = fmaf(qb.x, bflo(kv.z), s); s = fmaf(qb.y, bfhi(kv.z), s);
    s = fmaf(qb.z, bflo(kv.w), s); s = fmaf(qb.w, bfhi(kv.w), s);
    s += __shfl_xor(s, 1);          // r0+r1 (K full dot); r2+r3 garbage unused
    if (r == 0)
      sc[q_l*104 + g + it*8] = ((msk >> it) & 1) ? -1e9f : s * 0.25f;
  }
  __syncthreads();
  // Softmax per query: 16 lanes over 96 keys.
  if (t < 128) {
    const int q = t >> 4, l = t & 15;
    float mx = -3e38f;
    #pragma unroll
    for (int k = l; k < KK; k += 16) mx = fmaxf(mx, sc[q*104 + k]);
    #pragma unroll
    for (int m = 8; m >= 1; m >>= 1) mx = fmaxf(mx, __shfl_xor(mx, m));
    float sum = 0.0f;
    #pragma unroll
    for (int k = l; k < KK; k += 16) {
      const float p = __expf(sc[q*104 + k] - mx);   // masked -> exactly 0
      sc[q*104 + k] = p;
      sum += p;
    }
    #pragma unroll
    for (int m = 8; m >= 1; m >>= 1) sum += __shfl_xor(sum, m);
    if (l == 0) rden[q] = 1.0f / sum;
  }
  __syncthreads();
  // ctx: r2/r3 lanes accumulate their V half over their 12 keys.
  {
    float acc[8] = {0,0,0,0,0,0,0,0};
    #pragma unroll
    for (int it = 0; it < 12; it++) {
      const float wg = sc[q_l*104 + g + it*8];   // broadcast within quad
      const uint4 kv = kvbuf[it];
      acc[0] = fmaf(wg, bflo(kv.x), acc[0]); acc[1] = fmaf(wg, bfhi(kv.x), acc[1]);
      acc[2] = fmaf(wg, bflo(kv.y), acc[2]); acc[3] = fmaf(wg, bfhi(kv.y), acc[3]);
      acc[4] = fmaf(wg, bflo(kv.z), acc[4]); acc[5] = fmaf(wg, bfhi(kv.z), acc[5]);
      acc[6] = fmaf(wg, bflo(kv.w), acc[6]); acc[7] = fmaf(wg, bfhi(kv.w), acc[7]);
    }
    if (r >= 2) {
      const int slot = q_l*16 + g*2 + (r - 2);   // 0..127
      #pragma unroll
      for (int u = 0; u < 8; u++) red[slot][u] = acc[u];
    }
  }
  __syncthreads();
  // Reduce 8 slot-groups per (query, channel) and store.
  if (t < 128) {
    const int q = t >> 4, d = t & 15;
    const int half = d >> 3, u = d & 7;
    float s = 0.0f;
    #pragma unroll
    for (int gg = 0; gg < 8; gg++) s += red[q*16 + gg*2 + half][u];
    ctxg[(size_t)(n0 + q)*CH + h*16 + d] = s * rden[q];
  }
  // Warm-load consumption (impossible condition; waitcnt lands here, after
  // all useful work, so the warm never stalls the block).
  const unsigned accw = wv.x ^ wv.y ^ wv.z ^ wv.w;
  if (accw == 0x9E3779B9u && t == 255) sink[0] = accw;
}

// ---------------------------------------------------------------------------
// Kernel 4: epilogue via MFMA bf16 (unchanged).
// ---------------------------------------------------------------------------
__global__ __launch_bounds__(256) void k_epi(
    const float* __restrict__ ctxg, const __hip_bfloat16* __restrict__ Eb,
    const float* __restrict__ ob,
    const float* __restrict__ n2g, const float* __restrict__ n2b,
    const float* __restrict__ l1b, const float* __restrict__ l2b,
    const float* __restrict__ fb,
    float* __restrict__ outp) {
  __shared__ unsigned short csb[16][136];
  __shared__ float attnS[16][132];
  __shared__ unsigned short hb[16][136];
  __shared__ unsigned short a1b[16][264];
  __shared__ unsigned short xb[16][136];
  const unsigned short* owb  = reinterpret_cast<const unsigned short*>(Eb);
  const unsigned short* l1wb = owb + 16384;
  const unsigned short* l2wb = owb + 49152;
  const unsigned short* fwb  = owb + 81920;

  const int t = threadIdx.x;
  const int w = t >> 6;
  const int lane = t & 63;
  const int col = lane & 15;
  const int quad = lane >> 4;
  const int qbase = blockIdx.x * 16;

  {
    const int e = t * 8;
    const int row = e >> 7, cc = e & 127;
    const float4* src = reinterpret_cast<const float4*>(ctxg + (size_t)(qbase+row)*CH + cc);
    const float4 x0 = src[0], x1 = src[1];
    *reinterpret_cast<uint4*>(&csb[row][cc]) =
        make_uint4(pack2(x0.x,x0.y), pack2(x0.z,x0.w), pack2(x1.x,x1.y), pack2(x1.z,x1.w));
  }
  __syncthreads();
  {
    short8 af[4];
    #pragma unroll
    for (int kq = 0; kq < 4; kq++)
      af[kq] = *reinterpret_cast<const short8*>(&csb[col][quad*8 + kq*32]);
    #pragma unroll
    for (int j = 0; j < 2; j++) {
      const int n0 = w*32 + j*16;
      const float bia = ob[n0 + col];
      float4v acc = (float4v){bia, bia, bia, bia};
      #pragma unroll
      for (int kq = 0; kq < 4; kq++) {
        const short8 bf = *reinterpret_cast<const short8*>(
            owb + (size_t)(n0 + col)*CH + kq*32 + quad*8);
        acc = __builtin_amdgcn_mfma_f32_16x16x32_bf16(af[kq], bf, acc, 0, 0, 0);
      }
      #pragma unroll
      for (int r = 0; r < 4; r++) attnS[quad*4 + r][n0 + col] = acc[r];
    }
  }
  __syncthreads();
  {
    const int row = t >> 4, l = t & 15;
    float s = 0.0f, ss = 0.0f;
    #pragma unroll
    for (int c = l; c < CH; c += 16) { const float x = attnS[row][c]; s += x; ss += x*x; }
    #pragma unroll
    for (int m = 8; m >= 1; m >>= 1) { s += __shfl_xor(s, m); ss += __shfl_xor(ss, m); }
    const float mean = s * (1.0f/CH);
    const float var  = ss * (1.0f/CH) - mean*mean;
    const float rstd = 1.0f / sqrtf(var + 1e-5f);
    #pragma unroll
    for (int c = l; c < CH; c += 16)
      hb[row][c] = f2bf((attnS[row][c] - mean) * rstd * n2g[c] + n2b[c]);
  }
  __syncthreads();
  {
    short8 af[4];
    #pragma unroll
    for (int kq = 0; kq < 4; kq++)
      af[kq] = *reinterpret_cast<const short8*>(&hb[col][quad*8 + kq*32]);
    #pragma unroll
    for (int j = 0; j < 4; j++) {
      const int n0 = w*64 + j*16;
      const float bia = l1b[n0 + col];
      float4v acc = (float4v){bia, bia, bia, bia};
      #pragma unroll
      for (int kq = 0; kq < 4; kq++) {
        const short8 bf = *reinterpret_cast<const short8*>(
            l1wb + (size_t)(n0 + col)*CH + kq*32 + quad*8);
        acc = __builtin_amdgcn_mfma_f32_16x16x32_bf16(af[kq], bf, acc, 0, 0, 0);
      }
      #pragma unroll
      for (int r = 0; r < 4; r++)
        a1b[quad*4 + r][n0 + col] = f2bf(fmaxf(acc[r], 0.0f));
    }
  }
  __syncthreads();
  {
    short8 af[8];
    #pragma unroll
    for (int kq = 0; kq < 8; kq++)
      af[kq] = *reinterpret_cast<const short8*>(&a1b[col][quad*8 + kq*32]);
    #pragma unroll
    for (int j = 0; j < 2; j++) {
      const int n0 = w*32 + j*16;
      const float bia = l2b[n0 + col];
      float4v acc = (float4v){bia, bia, bia, bia};
      #pragma unroll
      for (int kq = 0; kq < 8; kq++) {
        const short8 bf = *reinterpret_cast<const short8*>(
            l2wb + (size_t)(n0 + col)*FFD + kq*32 + quad*8);
        acc = __builtin_amdgcn_mfma_f32_16x16x32_bf16(af[kq], bf, acc, 0, 0, 0);
      }
      #pragma unroll
      for (int r = 0; r < 4; r++)
        xb[quad*4 + r][n0 + col] = f2bf(acc[r] + attnS[quad*4 + r][n0 + col]);
    }
  }
  __syncthreads();
  {
    short8 af[4];
    #pragma unroll
    for (int kq = 0; kq < 4; kq++)
      af[kq] = *reinterpret_cast<const short8*>(&xb[col][quad*8 + kq*32]);
    #pragma unroll
    for (int j = 0; j < 2; j++) {
      const int n0 = w*32 + j*16;
      const float bia = fb[n0 + col];
      float4v acc = (float4v){bia, bia, bia, bia};
      #pragma unroll
      for (int kq = 0; kq < 4; kq++) {
        const short8 bf = *reinterpret_cast<const short8*>(
            fwb + (size_t)(n0 + col)*CH + kq*32 + quad*8);
        acc = __builtin_amdgcn_mfma_f32_16x16x32_bf16(af[kq], bf, acc, 0, 0, 0);
      }
      #pragma unroll
      for (int r = 0; r < 4; r++)
        outp[(size_t)(qbase + quad*4 + r)*CH + n0 + col] = fmaxf(acc[r], 0.0f);
    }
  }
}

// ---------------------------------------------------------------------------
extern "C" void kernel_launch(void* const* d_in, const int* in_sizes, int n_in,
                              void* d_out, int out_size, void* d_ws, size_t ws_size,
                              hipStream_t stream) {
  const float* vfeat  = (const float*)d_in[0];
  const float* vcoord = (const float*)d_in[1];
  const float* qcoord = (const float*)d_in[2];
  const int*   kidx   = (const int*)  d_in[3];
  const float* n1g    = (const float*)d_in[4];
  const float* n1b    = (const float*)d_in[5];
  const float* qpw    = (const float*)d_in[6];
  const float* qpb    = (const float*)d_in[7];
  const float* kpw    = (const float*)d_in[8];
  const float* kpb    = (const float*)d_in[9];
  const float* in_w   = (const float*)d_in[10];
  const float* in_b   = (const float*)d_in[11];
  const float* out_w  = (const float*)d_in[12];
  const float* out_b  = (const float*)d_in[13];
  const float* n2g    = (const float*)d_in[14];
  const float* n2b    = (const float*)d_in[15];
  const float* l1w    = (const float*)d_in[16];
  const float* l1b    = (const float*)d_in[17];
  const float* l2w    = (const float*)d_in[18];
  const float* l2b    = (const float*)d_in[19];
  const float* fw     = (const float*)d_in[20];
  const float* fb     = (const float*)d_in[21];
  float* out = (float*)d_out;

  unsigned short* KVh = (unsigned short*)d_ws;          // 8*NVOX*32 shorts (20.5 MB)
  __hip_bfloat16* Gb = (__hip_bfloat16*)(KVh + (size_t)8*NVOX*32);  // NVOX*CH bf16
  __hip_bfloat16* Wb = Gb + (size_t)NVOX*CH;            // 256*CH bf16
  __hip_bfloat16* Eb = Wb + (size_t)2*CH*CH;            // 98304 bf16 epi weights
  float* qb = (float*)(Eb + 98304);                     // NQRY*CH f32
  float* cx = qb + (size_t)NQRY*CH;                     // NQRY*CH f32
  unsigned* sink = (unsigned*)(cx + (size_t)NQRY*CH);   // 1 dword DCE guard

  k_prep   <<<NVOX/16 + 32 + NQRY/16, 256, 0, stream>>>(
      vfeat, vcoord, n1g, n1b, kpw, kpb, in_w, in_b,
      out_w, l1w, l2w, fw, qcoord, qpw, qpb, Gb, Wb, Eb, qb);
  k_kv_gemm<<<(NVOX/64)*8, 256, 0, stream>>>(Gb, Wb, in_b, KVh);
  k_attn   <<<(NQRY/8)*8, 256, 0, stream>>>(KVh, qb, kidx, cx, sink);
  k_epi    <<<NQRY/16, 256, 0, stream>>>(cx, Eb, out_b, n2g, n2b, l1b, l2b, fb, out);
}